// Round 24
// baseline (271.277 us; speedup 1.0000x reference)
//
#include <hip/hip_runtime.h>
#include <stdint.h>

#define AS1 __attribute__((address_space(1)))
#define AS3 __attribute__((address_space(3)))

using bf16x8 = __attribute__((ext_vector_type(8))) short;
using f32x4  = __attribute__((ext_vector_type(4))) float;

// ---- helpers -------------------------------------------------------------
__device__ __forceinline__ unsigned short f2bf(float f) {
  union { float f; unsigned u; } v; v.f = f;
  return (unsigned short)((v.u + 0x7FFFu + ((v.u >> 16) & 1u)) >> 16); // RNE
}
__device__ __forceinline__ float bf2f(unsigned short h) {
  union { unsigned u; float f; } v; v.u = ((unsigned)h) << 16;
  return v.f;
}
// async global->LDS, 16B per lane; lds dest must be wave-uniform base (HW adds lane*16)
__device__ __forceinline__ void gload_lds16(const void* g, void* l) {
  __builtin_amdgcn_global_load_lds((AS1 const void*)g, (AS3 void*)l, 16, 0, 0);
}

// ---- fused fp32->bf16 convert (x + 4 weights) + RoPE tables, one launch ----
__global__ void k_cvt5(const float* __restrict__ x,  const float* __restrict__ wq,
                       const float* __restrict__ wk, const float* __restrict__ wv,
                       const float* __restrict__ wo,
                       unsigned short* __restrict__ xb,  unsigned short* __restrict__ wqb,
                       unsigned short* __restrict__ wkb, unsigned short* __restrict__ wvb,
                       unsigned short* __restrict__ wob,
                       float* __restrict__ ct, float* __restrict__ st) {
  int idx = blockIdx.x * blockDim.x + threadIdx.x;
  int stride = gridDim.x * blockDim.x;
  for (int i = idx; i < 6422528; i += stride) {
    if (i >= 6291456) { // rope tables
      int j = i - 6291456;
      int t = j >> 6, fi = j & 63;
      float invf = exp2f(-(float)fi * (13.287712379549449f / 64.0f));
      float a = (float)t * invf;
      ct[j] = cosf(a);
      st[j] = sinf(a);
      continue;
    }
    const float* src; unsigned short* dst; int off;
    if (i < 2097152) { src = x; dst = xb; off = i; }
    else {
      int j = i - 2097152;
      int w = j >> 20;            // 1,048,576 float4 per weight
      off = j & 1048575;
      src = (w == 0) ? wq : (w == 1) ? wk : (w == 2) ? wv : wo;
      dst = (w == 0) ? wqb : (w == 1) ? wkb : (w == 2) ? wvb : wob;
    }
    float4 f = ((const float4*)src)[off];
    ushort4 o;
    o.x = f2bf(f.x); o.y = f2bf(f.y); o.z = f2bf(f.z); o.w = f2bf(f.w);
    ((ushort4*)dst)[off] = o;
  }
}

// ---- RoPE apply in-place on q and k [BH, T, 128] bf16 ---------------------
// q pre-scaled by (1/sqrt(128))*log2(e): flash logits are base-2.
__global__ void k_rope(unsigned short* __restrict__ q, unsigned short* __restrict__ k,
                       const float* __restrict__ ct, const float* __restrict__ st) {
  const float SC2 = 0.12751659974141322f;
  int idx = blockIdx.x * blockDim.x + threadIdx.x;
  int i = idx & 63;
  int t = (idx >> 6) & 2047;
  int bh = idx >> 17;
  size_t base = ((size_t)bh * 2048 + t) * 128;
  float c = ct[t * 64 + i], s = st[t * 64 + i];
  {
    float x1 = bf2f(q[base + i]), x2 = bf2f(q[base + i + 64]);
    q[base + i]      = f2bf((x1 * c - x2 * s) * SC2);
    q[base + i + 64] = f2bf((x2 * c + x1 * s) * SC2);
  }
  {
    float x1 = bf2f(k[base + i]), x2 = bf2f(k[base + i + 64]);
    k[base + i]      = f2bf(x1 * c - x2 * s);
    k[base + i + 64] = f2bf(x2 * c + x1 * s);
  }
}

// ---- 256x128 GEMM, counted-vmcnt pipeline + T1 XCD swizzle -----------------
// r23's verified kernel + bijective XCD block remap (T1, m192/m204): each XCD
// gets a contiguous chunk of the grid so shared A-row-panels are fetched into
// ONE L2 instead of 8. FETCH was 110.7MB vs ~40MB ideal. Grids 768/256 both
// divide 8 -> simple (lin%8)*cpx + lin/8 remap is bijective.
// MODE 0: f32 out [M,2048] (Wo, grid 16x16).  MODE 1: QKV (grid 48x16).
template <int MODE>
__global__ __launch_bounds__(512, 2) void k_gemm256n128(
    const unsigned short* __restrict__ Ag,
    const unsigned short* __restrict__ B0,
    const unsigned short* __restrict__ B1,
    const unsigned short* __restrict__ B2,
    float* __restrict__ outF,
    unsigned short* __restrict__ outQ,
    unsigned short* __restrict__ outK,
    unsigned short* __restrict__ outVT) {
  // ush: A dbuf [2][16384] @0 | B dbuf [2][8192] @32768   (= 96 KiB)
  __shared__ __align__(16) unsigned short lds[49152];

  const int tid = threadIdx.x;
  const int wid = tid >> 6, lane = tid & 63;
  const int wm = wid >> 1, wn = wid & 1;      // 4M x 2N wave grid
  const int rowA = lane & 15, kg = lane >> 4;
  const int rgrp = kg * 4;
  const int swz = rowA & 7;

  // T1 XCD swizzle: contiguous grid chunk per XCD (bijective: nwg % 8 == 0)
  const int gridW = (MODE == 1) ? 48 : 16;
  const int nwg   = gridW * 16;
  const int cpx   = nwg >> 3;
  const int lin   = blockIdx.x + gridW * blockIdx.y;
  const int slin  = (lin & 7) * cpx + (lin >> 3);
  const int bx    = slin % gridW, by = slin / gridW;

  const int m0 = by * 256;
  const int n0g = bx * 128;
  int w, n0;
  const unsigned short* Bg;
  if (MODE == 0) { w = 0; n0 = n0g; Bg = B0; }
  else { w = n0g >> 11; n0 = n0g & 2047; Bg = (w == 0) ? B0 : (w == 1) ? B1 : B2; }

  const int aBase = wm * 4096 + rowA * 64;
  const int bBase = wn * 4096 + rowA * 64;
  const int ch0 = (kg ^ swz) * 8;
  const int ch1 = ((4 + kg) ^ swz) * 8;

  const int grow = wid * 8 + (lane >> 3);
  const int gch  = ((lane & 7) ^ ((lane >> 3) & 7)) * 8;
  const int sdst = wid * 512;

  auto SA = [&](int dst, int t1, int c4) {
    gload_lds16(Ag + (size_t)(m0 + c4 * 64 + grow) * 2048 + t1 * 64 + gch,
                (void*)&lds[dst * 16384 + c4 * 4096 + sdst]);
  };
  auto SB = [&](int dst, int t1, int c2) {
    gload_lds16(Bg + (size_t)(n0 + c2 * 64 + grow) * 2048 + t1 * 64 + gch,
                (void*)&lds[32768 + dst * 8192 + c2 * 4096 + sdst]);
  };
  auto STAGE = [&](int dst, int t1) { // 6 gloads: the per-tile unit
    SA(dst, t1, 0); SA(dst, t1, 1); SA(dst, t1, 2); SA(dst, t1, 3);
    SB(dst, t1, 0); SB(dst, t1, 1);
  };

  f32x4 acc[4][4];
  const f32x4 z4 = {0.f, 0.f, 0.f, 0.f};
#pragma unroll
  for (int i = 0; i < 4; ++i)
#pragma unroll
    for (int j = 0; j < 4; ++j) acc[i][j] = z4;

  // prologue: stage t0 -> buf0 and t1 -> buf1; gate t0 (t1's 6 stay in flight)
  STAGE(0, 0);
  STAGE(1, 1);
  asm volatile("s_waitcnt vmcnt(6)" ::: "memory");
  __builtin_amdgcn_s_barrier();
  __builtin_amdgcn_sched_barrier(0);

  for (int t = 0; t < 32; ++t) {
    const int c = t & 1;
    const int cA = c * 16384, cB = 32768 + c * 8192;
    bf16x8 af[4], bk[4];

    // ---- compute K-tile t from buf c (both kk halves, 32 MFMA) ----
    __builtin_amdgcn_s_setprio(1);
#pragma unroll
    for (int i = 0; i < 4; ++i) af[i] = *(const bf16x8*)&lds[cA + aBase + i * 1024 + ch0];
#pragma unroll
    for (int j = 0; j < 4; ++j) bk[j] = *(const bf16x8*)&lds[cB + bBase + j * 1024 + ch0];
#pragma unroll
    for (int i = 0; i < 4; ++i)
#pragma unroll
      for (int j = 0; j < 4; ++j)
        acc[i][j] = __builtin_amdgcn_mfma_f32_16x16x32_bf16(af[i], bk[j], acc[i][j], 0, 0, 0);
#pragma unroll
    for (int i = 0; i < 4; ++i) af[i] = *(const bf16x8*)&lds[cA + aBase + i * 1024 + ch1];
#pragma unroll
    for (int j = 0; j < 4; ++j) bk[j] = *(const bf16x8*)&lds[cB + bBase + j * 1024 + ch1];
#pragma unroll
    for (int i = 0; i < 4; ++i)
#pragma unroll
      for (int j = 0; j < 4; ++j)
        acc[i][j] = __builtin_amdgcn_mfma_f32_16x16x32_bf16(af[i], bk[j], acc[i][j], 0, 0, 0);
    __builtin_amdgcn_s_setprio(0);

    if (t < 31) {
      // all waves done reading buf c -> safe to overwrite
      asm volatile("s_waitcnt lgkmcnt(0)" ::: "memory");
      __builtin_amdgcn_s_barrier();
      __builtin_amdgcn_sched_barrier(0);
      if (t + 2 < 32) {
        STAGE(c, t + 2);                                  // into freed buf c
        asm volatile("s_waitcnt vmcnt(6)" ::: "memory");  // t+1 retired
      } else {
        asm volatile("s_waitcnt vmcnt(0)" ::: "memory");  // tail: drain t+1
      }
      __builtin_amdgcn_s_barrier();                       // publish t+1
      __builtin_amdgcn_sched_barrier(0);
    }
  }

  // ---- epilogue ----
#pragma unroll
  for (int i = 0; i < 4; ++i) {
#pragma unroll
    for (int j = 0; j < 4; ++j) {
      const int gm0 = m0 + wm * 64 + i * 16 + rgrp;
      const int gn  = n0 + wn * 64 + j * 16 + rowA;
      if (MODE == 0) {
#pragma unroll
        for (int r = 0; r < 4; ++r)
          outF[(size_t)(gm0 + r) * 2048 + gn] = acc[i][j][r];
      } else if (w == 2) { // transposed V
        int h = gn >> 7, dd = gn & 127;
        int b = gm0 >> 11, tt = gm0 & 2047;
        ushort4 pk;
        pk.x = f2bf(acc[i][j][0]); pk.y = f2bf(acc[i][j][1]);
        pk.z = f2bf(acc[i][j][2]); pk.w = f2bf(acc[i][j][3]);
        *(ushort4*)&outVT[(((size_t)(b * 16 + h)) * 128 + dd) * 2048 + tt] = pk;
      } else {
        unsigned short* C = w ? outK : outQ;
        int h = gn >> 7, dd = gn & 127;
        int b = gm0 >> 11, tt = gm0 & 2047;
#pragma unroll
        for (int r = 0; r < 4; ++r)
          C[(((size_t)(b * 16 + h)) * 2048 + tt + r) * 128 + dd] = f2bf(acc[i][j][r]);
      }
    }
  }
}

// ---- flash attention fwd: EXACT r21 kernel (8 waves x 16 q-rows, ~100us) ---
__global__ __launch_bounds__(512) void k_flash(const unsigned short* __restrict__ q,
                                               const unsigned short* __restrict__ k,
                                               const unsigned short* __restrict__ vt,
                                               unsigned short* __restrict__ obt) {
  // ush: K[16384] @0 (P overlays [0,8192)) | V[16384] @16384   (= 64 KiB)
  __shared__ __align__(16) unsigned short lds[32768];

  const int tid = threadIdx.x;
  const int wid = tid >> 6, lane = tid & 63;   // wid 0..7
  const int rowA = lane & 15, kg = lane >> 4;
  const int kgrp = kg * 8, rgrp = kg * 4;

  const int bid = blockIdx.x;          // 0..255
  const int xcd = bid & 7;             // round-robin XCD dispatch (perf-only)
  const int r0  = bid >> 3;            // 0..31
  const int bh  = xcd * 4 + (r0 & 3);  // 4 heads per XCD chunk
  const int p   = r0 >> 2;             // 0..7
  const int b = bh >> 4, h = bh & 15;

  const int jbs[2] = {15 - p, p};      // heavy segment first
  const int nt0 = jbs[0] + 1, nt1 = jbs[1] + 1;
  const int total = nt0 + nt1;         // = 17 for every block

  const unsigned short* qh  = q  + (size_t)bh * 2048 * 128;
  const unsigned short* kh  = k  + (size_t)bh * 2048 * 128;
  const unsigned short* vth = vt + (size_t)bh * 128 * 2048;

  const int srow4 = wid * 4 + (lane >> 4); // 0..31
  auto STAGE_K = [&](int kv0) {
#pragma unroll
    for (int c = 0; c < 4; ++c) {
      int row = c * 32 + srow4;
      int ch  = (lane & 15) ^ (row & 7);
      gload_lds16(kh + (size_t)(kv0 + row) * 128 + ch * 8,
                  (void*)&lds[(c * 32 + wid * 4) * 128]);
    }
  };
  auto STAGE_V = [&](int kv0) {
#pragma unroll
    for (int c = 0; c < 4; ++c) {
      int row = c * 32 + srow4;            // d-dim row
      int ch  = (lane & 15) ^ (row & 7);
      gload_lds16(vth + (size_t)row * 2048 + kv0 + ch * 8,
                  (void*)&lds[16384 + (c * 32 + wid * 4) * 128]);
    }
  };

  const f32x4 z4 = {0.f, 0.f, 0.f, 0.f};
  bf16x8 qf[4];
  f32x4 o[8];
  float mprev[4], lsum[4];
  int q0w = 0;

  int seg = 0, it = 0;
  STAGE_K(0);   // 4 oldest vmem ops/thread
  STAGE_V(0);   // 4 newest

  for (int u = 0; u < total; ++u) {
    const int nt = (seg == 0) ? nt0 : nt1;
    const int kv0 = it * 128;

    // ---- top gate: K(u) complete everywhere; V(u) may still fly ----
    asm volatile("s_waitcnt vmcnt(4)" ::: "memory");
    __builtin_amdgcn_s_barrier();
    __builtin_amdgcn_sched_barrier(0);

    if (it == 0) {   // segment init: Q fragments (16 rows/wave) + state reset
      q0w = jbs[seg] * 128 + wid * 16;
#pragma unroll
      for (int kq = 0; kq < 4; ++kq)
        qf[kq] = *(const bf16x8*)(qh + (size_t)(q0w + rowA) * 128 + kq * 32 + kgrp);
#pragma unroll
      for (int dn = 0; dn < 8; ++dn) o[dn] = z4;
#pragma unroll
      for (int r2 = 0; r2 < 4; ++r2) { mprev[r2] = -1e30f; lsum[r2] = 0.f; }
    }

    // ---- S = Q K^T over 128 kv (swizzled LDS) ----
    f32x4 s[8];
#pragma unroll
    for (int n = 0; n < 8; ++n) s[n] = z4;
    __builtin_amdgcn_s_setprio(1);
#pragma unroll
    for (int kq = 0; kq < 4; ++kq) {
#pragma unroll
      for (int n = 0; n < 8; ++n) {
        int row = n * 16 + rowA;
        int ch  = (kq * 4 + kg) ^ (row & 7);
        bf16x8 bkk = *(const bf16x8*)&lds[row * 128 + ch * 8];
        s[n] = __builtin_amdgcn_mfma_f32_16x16x32_bf16(qf[kq], bkk, s[n], 0, 0, 0);
      }
    }
    __builtin_amdgcn_s_setprio(0);

    // ---- mid gate: V(u) drained + K reads done -> P region free, V visible
    asm volatile("s_waitcnt vmcnt(0) lgkmcnt(0)" ::: "memory");
    __builtin_amdgcn_s_barrier();
    __builtin_amdgcn_sched_barrier(0);

    // ---- causal mask (only the diagonal tile) ----
    if (kv0 + 127 > q0w) {
#pragma unroll
      for (int n = 0; n < 8; ++n)
#pragma unroll
        for (int r2 = 0; r2 < 4; ++r2) {
          int qg = q0w + rgrp + r2;
          int kgl = kv0 + n * 16 + rowA;
          if (kgl > qg) s[n][r2] = -1e30f;
        }
    }

    // ---- online softmax (base-2), step-major trees, defer-max ----
    float tmax[4];
#pragma unroll
    for (int r2 = 0; r2 < 4; ++r2) {
      float t = s[0][r2];
#pragma unroll
      for (int n = 1; n < 8; ++n) t = fmaxf(t, s[n][r2]);
      tmax[r2] = t;
    }
#pragma unroll
    for (int stp = 1; stp <= 8; stp <<= 1)
#pragma unroll
      for (int r2 = 0; r2 < 4; ++r2)
        tmax[r2] = fmaxf(tmax[r2], __shfl_xor(tmax[r2], stp));

    bool ok = true;
#pragma unroll
    for (int r2 = 0; r2 < 4; ++r2) ok = ok && (tmax[r2] <= mprev[r2] + 8.0f);
    const bool skip = __all(ok ? 1 : 0);

    float mnew[4], psum[4];
#pragma unroll
    for (int r2 = 0; r2 < 4; ++r2) {
      mnew[r2] = skip ? mprev[r2] : fmaxf(mprev[r2], tmax[r2]);
      float ps = 0.f;
#pragma unroll
      for (int n = 0; n < 8; ++n) {
        float pv = exp2f(s[n][r2] - mnew[r2]);
        s[n][r2] = pv;
        ps += pv;
      }
      psum[r2] = ps;
    }
#pragma unroll
    for (int stp = 1; stp <= 8; stp <<= 1)
#pragma unroll
      for (int r2 = 0; r2 < 4; ++r2)
        psum[r2] += __shfl_xor(psum[r2], stp);

#pragma unroll
    for (int r2 = 0; r2 < 4; ++r2) {
      if (skip) {
        lsum[r2] += psum[r2];
      } else {
        float alpha = exp2f(mprev[r2] - mnew[r2]);
        lsum[r2] = lsum[r2] * alpha + psum[r2];
        mprev[r2] = mnew[r2];
#pragma unroll
        for (int dn = 0; dn < 8; ++dn) o[dn][r2] *= alpha;
      }
    }

    // ---- PV in two passes; P [16][64]/wave overlays Kbuf[0..8192 ush) ----
    unsigned short* Pw = &lds[wid * 1024];
    const unsigned short* Vb = &lds[16384];
#pragma unroll
    for (int pass = 0; pass < 2; ++pass) {
#pragma unroll
      for (int nl = 0; nl < 4; ++nl)
#pragma unroll
        for (int r2 = 0; r2 < 4; ++r2) {
          int row = rgrp + r2;
          int col = nl * 16 + rowA;
          Pw[row * 64 + (col ^ ((row & 7) << 3))] = f2bf(s[pass * 4 + nl][r2]);
        }
      // per-wave DS ordering: compiler inserts lgkmcnt waits before reads
      __builtin_amdgcn_s_setprio(1);
#pragma unroll
      for (int kkl = 0; kkl < 2; ++kkl) {
        const int kk = pass * 2 + kkl;
        bf16x8 pa;
        {
          int row = rowA;
          int col0 = kkl * 32 + kgrp;
          pa = *(const bf16x8*)&Pw[row * 64 + (col0 ^ ((row & 7) << 3))];
        }
#pragma unroll
        for (int dn = 0; dn < 8; ++dn) {
          int row = dn * 16 + rowA;
          int ch  = (kk * 4 + kg) ^ (row & 7);
          bf16x8 vb = *(const bf16x8*)&Vb[row * 128 + ch * 8];
          o[dn] = __builtin_amdgcn_mfma_f32_16x16x32_bf16(pa, vb, o[dn], 0, 0, 0);
        }
      }
      __builtin_amdgcn_s_setprio(0);
    }

    // ---- segment epilogue: normalize and write ----
    if (it == nt - 1) {
      float rinv[4];
#pragma unroll
      for (int r2 = 0; r2 < 4; ++r2) rinv[r2] = 1.0f / lsum[r2];
#pragma unroll
      for (int dn = 0; dn < 8; ++dn)
#pragma unroll
        for (int r2 = 0; r2 < 4; ++r2) {
          float v = o[dn][r2] * rinv[r2];
          int t = q0w + rgrp + r2;
          int col = h * 128 + dn * 16 + rowA;
          obt[((size_t)b * 2048 + t) * 2048 + col] = f2bf(v);
        }
    }

    __syncthreads(); // drains everything (vmcnt0+lgkmcnt0); buffers reusable

    // ---- stage next K and V (K first = oldest; gated at next top) ----
    if (u + 1 < total) {
      const int itn = (u + 1 >= nt0) ? (u + 1 - nt0) : (u + 1);
      STAGE_K(itn * 128);
      STAGE_V(itn * 128);
    }

    ++it;
    if (seg == 0 && it == nt0) { seg = 1; it = 0; }
  }
}

// ---- host launch -----------------------------------------------------------
extern "C" void kernel_launch(void* const* d_in, const int* in_sizes, int n_in,
                              void* d_out, int out_size, void* d_ws, size_t ws_size,
                              hipStream_t stream) {
  const float* x  = (const float*)d_in[0];
  const float* Wq = (const float*)d_in[2];
  const float* Wk = (const float*)d_in[3];
  const float* Wv = (const float*)d_in[4];
  const float* Wo = (const float*)d_in[5];
  float* out = (float*)d_out;

  char* ws = (char*)d_ws;
  unsigned short* xb  = (unsigned short*)(ws + 0);
  unsigned short* wqb = (unsigned short*)(ws + 16777216);
  unsigned short* wkb = (unsigned short*)(ws + 25165824);
  unsigned short* wvb = (unsigned short*)(ws + 33554432);
  unsigned short* wob = (unsigned short*)(ws + 41943040);
  unsigned short* qb  = (unsigned short*)(ws + 50331648);
  unsigned short* kb  = (unsigned short*)(ws + 67108864);
  unsigned short* vtb = (unsigned short*)(ws + 83886080);
  unsigned short* obt = (unsigned short*)(ws + 100663296);
  float* ct = (float*)(ws + 117440512);
  float* st = (float*)(ws + 117964800);

  k_cvt5<<<2048, 256, 0, stream>>>(x, Wq, Wk, Wv, Wo, xb, wqb, wkb, wvb, wob, ct, st);
  dim3 gq(48, 16); // merged QKV: 768 blocks = 3 even rounds (+ XCD swizzle)
  k_gemm256n128<1><<<gq, 512, 0, stream>>>(xb, wqb, wkb, wvb, nullptr, qb, kb, vtb);
  k_rope<<<16384, 256, 0, stream>>>(qb, kb, ct, st);
  k_flash<<<256, 512, 0, stream>>>(qb, kb, vtb, obt);
  dim3 go(16, 16); // Wo: 256 blocks = 1 full-chip round (+ XCD swizzle)
  k_gemm256n128<0><<<go, 512, 0, stream>>>(obt, wob, nullptr, nullptr, out, nullptr, nullptr, nullptr);
}

// Round 25
// 269.532 us; speedup vs baseline: 1.0065x; 1.0065x over previous
//
#include <hip/hip_runtime.h>
#include <stdint.h>

#define AS1 __attribute__((address_space(1)))
#define AS3 __attribute__((address_space(3)))

using bf16x8 = __attribute__((ext_vector_type(8))) short;
using f32x4  = __attribute__((ext_vector_type(4))) float;

// ---- helpers -------------------------------------------------------------
__device__ __forceinline__ unsigned short f2bf(float f) {
  union { float f; unsigned u; } v; v.f = f;
  return (unsigned short)((v.u + 0x7FFFu + ((v.u >> 16) & 1u)) >> 16); // RNE
}
__device__ __forceinline__ float bf2f(unsigned short h) {
  union { unsigned u; float f; } v; v.u = ((unsigned)h) << 16;
  return v.f;
}
// async global->LDS, 16B per lane; lds dest must be wave-uniform base (HW adds lane*16)
__device__ __forceinline__ void gload_lds16(const void* g, void* l) {
  __builtin_amdgcn_global_load_lds((AS1 const void*)g, (AS3 void*)l, 16, 0, 0);
}

// ---- fused fp32->bf16 convert (x + 4 weights) + RoPE tables, one launch ----
__global__ void k_cvt5(const float* __restrict__ x,  const float* __restrict__ wq,
                       const float* __restrict__ wk, const float* __restrict__ wv,
                       const float* __restrict__ wo,
                       unsigned short* __restrict__ xb,  unsigned short* __restrict__ wqb,
                       unsigned short* __restrict__ wkb, unsigned short* __restrict__ wvb,
                       unsigned short* __restrict__ wob,
                       float* __restrict__ ct, float* __restrict__ st) {
  int idx = blockIdx.x * blockDim.x + threadIdx.x;
  int stride = gridDim.x * blockDim.x;
  for (int i = idx; i < 6422528; i += stride) {
    if (i >= 6291456) { // rope tables
      int j = i - 6291456;
      int t = j >> 6, fi = j & 63;
      float invf = exp2f(-(float)fi * (13.287712379549449f / 64.0f));
      float a = (float)t * invf;
      ct[j] = cosf(a);
      st[j] = sinf(a);
      continue;
    }
    const float* src; unsigned short* dst; int off;
    if (i < 2097152) { src = x; dst = xb; off = i; }
    else {
      int j = i - 2097152;
      int w = j >> 20;            // 1,048,576 float4 per weight
      off = j & 1048575;
      src = (w == 0) ? wq : (w == 1) ? wk : (w == 2) ? wv : wo;
      dst = (w == 0) ? wqb : (w == 1) ? wkb : (w == 2) ? wvb : wob;
    }
    float4 f = ((const float4*)src)[off];
    ushort4 o;
    o.x = f2bf(f.x); o.y = f2bf(f.y); o.z = f2bf(f.z); o.w = f2bf(f.w);
    ((ushort4*)dst)[off] = o;
  }
}

// ---- RoPE apply in-place on q and k [BH, T, 128] bf16 ---------------------
// q pre-scaled by (1/sqrt(128))*log2(e): flash logits are base-2.
__global__ void k_rope(unsigned short* __restrict__ q, unsigned short* __restrict__ k,
                       const float* __restrict__ ct, const float* __restrict__ st) {
  const float SC2 = 0.12751659974141322f;
  int idx = blockIdx.x * blockDim.x + threadIdx.x;
  int i = idx & 63;
  int t = (idx >> 6) & 2047;
  int bh = idx >> 17;
  size_t base = ((size_t)bh * 2048 + t) * 128;
  float c = ct[t * 64 + i], s = st[t * 64 + i];
  {
    float x1 = bf2f(q[base + i]), x2 = bf2f(q[base + i + 64]);
    q[base + i]      = f2bf((x1 * c - x2 * s) * SC2);
    q[base + i + 64] = f2bf((x2 * c + x1 * s) * SC2);
  }
  {
    float x1 = bf2f(k[base + i]), x2 = bf2f(k[base + i + 64]);
    k[base + i]      = f2bf(x1 * c - x2 * s);
    k[base + i + 64] = f2bf(x2 * c + x1 * s);
  }
}

// ---- 256x128 GEMM with T4 counted-vmcnt pipeline (EXACT r23; best) ---------
// Per K-tile: {compute from buf c -> lgkmcnt(0)+barrier (buf c reads done) ->
// stage t+2 into freed buf c -> vmcnt(6) (t+1 retired; t+2's 6 in flight) ->
// barrier}. vmcnt never drains to 0 mid-loop (T4). r24's XCD swizzle REVERTED:
// it doubled FETCH (213MB) with zero time delta — mapping model wrong, and the
// kernel is not memory-bound (27% HBM peak at 2x traffic, dur unchanged).
// MODE 0: f32 out [M,2048] (Wo, grid 16x16).  MODE 1: QKV (grid 48x16).
template <int MODE>
__global__ __launch_bounds__(512, 2) void k_gemm256n128(
    const unsigned short* __restrict__ Ag,
    const unsigned short* __restrict__ B0,
    const unsigned short* __restrict__ B1,
    const unsigned short* __restrict__ B2,
    float* __restrict__ outF,
    unsigned short* __restrict__ outQ,
    unsigned short* __restrict__ outK,
    unsigned short* __restrict__ outVT) {
  // ush: A dbuf [2][16384] @0 | B dbuf [2][8192] @32768   (= 96 KiB)
  __shared__ __align__(16) unsigned short lds[49152];

  const int tid = threadIdx.x;
  const int wid = tid >> 6, lane = tid & 63;
  const int wm = wid >> 1, wn = wid & 1;      // 4M x 2N wave grid
  const int rowA = lane & 15, kg = lane >> 4;
  const int rgrp = kg * 4;
  const int swz = rowA & 7;

  const int m0 = blockIdx.y * 256;
  const int n0g = blockIdx.x * 128;
  int w, n0;
  const unsigned short* Bg;
  if (MODE == 0) { w = 0; n0 = n0g; Bg = B0; }
  else { w = n0g >> 11; n0 = n0g & 2047; Bg = (w == 0) ? B0 : (w == 1) ? B1 : B2; }

  const int aBase = wm * 4096 + rowA * 64;
  const int bBase = wn * 4096 + rowA * 64;
  const int ch0 = (kg ^ swz) * 8;
  const int ch1 = ((4 + kg) ^ swz) * 8;

  const int grow = wid * 8 + (lane >> 3);
  const int gch  = ((lane & 7) ^ ((lane >> 3) & 7)) * 8;
  const int sdst = wid * 512;

  auto SA = [&](int dst, int t1, int c4) {
    gload_lds16(Ag + (size_t)(m0 + c4 * 64 + grow) * 2048 + t1 * 64 + gch,
                (void*)&lds[dst * 16384 + c4 * 4096 + sdst]);
  };
  auto SB = [&](int dst, int t1, int c2) {
    gload_lds16(Bg + (size_t)(n0 + c2 * 64 + grow) * 2048 + t1 * 64 + gch,
                (void*)&lds[32768 + dst * 8192 + c2 * 4096 + sdst]);
  };
  auto STAGE = [&](int dst, int t1) { // 6 gloads: the per-tile unit
    SA(dst, t1, 0); SA(dst, t1, 1); SA(dst, t1, 2); SA(dst, t1, 3);
    SB(dst, t1, 0); SB(dst, t1, 1);
  };

  f32x4 acc[4][4];
  const f32x4 z4 = {0.f, 0.f, 0.f, 0.f};
#pragma unroll
  for (int i = 0; i < 4; ++i)
#pragma unroll
    for (int j = 0; j < 4; ++j) acc[i][j] = z4;

  // prologue: stage t0 -> buf0 and t1 -> buf1; gate t0 (t1's 6 stay in flight)
  STAGE(0, 0);
  STAGE(1, 1);
  asm volatile("s_waitcnt vmcnt(6)" ::: "memory");
  __builtin_amdgcn_s_barrier();
  __builtin_amdgcn_sched_barrier(0);

  for (int t = 0; t < 32; ++t) {
    const int c = t & 1;
    const int cA = c * 16384, cB = 32768 + c * 8192;
    bf16x8 af[4], bk[4];

    // ---- compute K-tile t from buf c (both kk halves, 32 MFMA) ----
    __builtin_amdgcn_s_setprio(1);
#pragma unroll
    for (int i = 0; i < 4; ++i) af[i] = *(const bf16x8*)&lds[cA + aBase + i * 1024 + ch0];
#pragma unroll
    for (int j = 0; j < 4; ++j) bk[j] = *(const bf16x8*)&lds[cB + bBase + j * 1024 + ch0];
#pragma unroll
    for (int i = 0; i < 4; ++i)
#pragma unroll
      for (int j = 0; j < 4; ++j)
        acc[i][j] = __builtin_amdgcn_mfma_f32_16x16x32_bf16(af[i], bk[j], acc[i][j], 0, 0, 0);
#pragma unroll
    for (int i = 0; i < 4; ++i) af[i] = *(const bf16x8*)&lds[cA + aBase + i * 1024 + ch1];
#pragma unroll
    for (int j = 0; j < 4; ++j) bk[j] = *(const bf16x8*)&lds[cB + bBase + j * 1024 + ch1];
#pragma unroll
    for (int i = 0; i < 4; ++i)
#pragma unroll
      for (int j = 0; j < 4; ++j)
        acc[i][j] = __builtin_amdgcn_mfma_f32_16x16x32_bf16(af[i], bk[j], acc[i][j], 0, 0, 0);
    __builtin_amdgcn_s_setprio(0);

    if (t < 31) {
      // all waves done reading buf c -> safe to overwrite
      asm volatile("s_waitcnt lgkmcnt(0)" ::: "memory");
      __builtin_amdgcn_s_barrier();
      __builtin_amdgcn_sched_barrier(0);
      if (t + 2 < 32) {
        STAGE(c, t + 2);                                  // into freed buf c
        asm volatile("s_waitcnt vmcnt(6)" ::: "memory");  // t+1 retired
      } else {
        asm volatile("s_waitcnt vmcnt(0)" ::: "memory");  // tail: drain t+1
      }
      __builtin_amdgcn_s_barrier();                       // publish t+1
      __builtin_amdgcn_sched_barrier(0);
    }
  }

  // ---- epilogue ----
#pragma unroll
  for (int i = 0; i < 4; ++i) {
#pragma unroll
    for (int j = 0; j < 4; ++j) {
      const int gm0 = m0 + wm * 64 + i * 16 + rgrp;
      const int gn  = n0 + wn * 64 + j * 16 + rowA;
      if (MODE == 0) {
#pragma unroll
        for (int r = 0; r < 4; ++r)
          outF[(size_t)(gm0 + r) * 2048 + gn] = acc[i][j][r];
      } else if (w == 2) { // transposed V
        int h = gn >> 7, dd = gn & 127;
        int b = gm0 >> 11, tt = gm0 & 2047;
        ushort4 pk;
        pk.x = f2bf(acc[i][j][0]); pk.y = f2bf(acc[i][j][1]);
        pk.z = f2bf(acc[i][j][2]); pk.w = f2bf(acc[i][j][3]);
        *(ushort4*)&outVT[(((size_t)(b * 16 + h)) * 128 + dd) * 2048 + tt] = pk;
      } else {
        unsigned short* C = w ? outK : outQ;
        int h = gn >> 7, dd = gn & 127;
        int b = gm0 >> 11, tt = gm0 & 2047;
#pragma unroll
        for (int r = 0; r < 4; ++r)
          C[(((size_t)(b * 16 + h)) * 2048 + tt + r) * 128 + dd] = f2bf(acc[i][j][r]);
      }
    }
  }
}

// ---- flash attention fwd: EXACT r21 kernel (8 waves x 16 q-rows, ~100us) ---
__global__ __launch_bounds__(512) void k_flash(const unsigned short* __restrict__ q,
                                               const unsigned short* __restrict__ k,
                                               const unsigned short* __restrict__ vt,
                                               unsigned short* __restrict__ obt) {
  // ush: K[16384] @0 (P overlays [0,8192)) | V[16384] @16384   (= 64 KiB)
  __shared__ __align__(16) unsigned short lds[32768];

  const int tid = threadIdx.x;
  const int wid = tid >> 6, lane = tid & 63;   // wid 0..7
  const int rowA = lane & 15, kg = lane >> 4;
  const int kgrp = kg * 8, rgrp = kg * 4;

  const int bid = blockIdx.x;          // 0..255
  const int xcd = bid & 7;             // round-robin XCD dispatch (perf-only)
  const int r0  = bid >> 3;            // 0..31
  const int bh  = xcd * 4 + (r0 & 3);  // 4 heads per XCD chunk
  const int p   = r0 >> 2;             // 0..7
  const int b = bh >> 4, h = bh & 15;

  const int jbs[2] = {15 - p, p};      // heavy segment first
  const int nt0 = jbs[0] + 1, nt1 = jbs[1] + 1;
  const int total = nt0 + nt1;         // = 17 for every block

  const unsigned short* qh  = q  + (size_t)bh * 2048 * 128;
  const unsigned short* kh  = k  + (size_t)bh * 2048 * 128;
  const unsigned short* vth = vt + (size_t)bh * 128 * 2048;

  const int srow4 = wid * 4 + (lane >> 4); // 0..31
  auto STAGE_K = [&](int kv0) {
#pragma unroll
    for (int c = 0; c < 4; ++c) {
      int row = c * 32 + srow4;
      int ch  = (lane & 15) ^ (row & 7);
      gload_lds16(kh + (size_t)(kv0 + row) * 128 + ch * 8,
                  (void*)&lds[(c * 32 + wid * 4) * 128]);
    }
  };
  auto STAGE_V = [&](int kv0) {
#pragma unroll
    for (int c = 0; c < 4; ++c) {
      int row = c * 32 + srow4;            // d-dim row
      int ch  = (lane & 15) ^ (row & 7);
      gload_lds16(vth + (size_t)row * 2048 + kv0 + ch * 8,
                  (void*)&lds[16384 + (c * 32 + wid * 4) * 128]);
    }
  };

  const f32x4 z4 = {0.f, 0.f, 0.f, 0.f};
  bf16x8 qf[4];
  f32x4 o[8];
  float mprev[4], lsum[4];
  int q0w = 0;

  int seg = 0, it = 0;
  STAGE_K(0);   // 4 oldest vmem ops/thread
  STAGE_V(0);   // 4 newest

  for (int u = 0; u < total; ++u) {
    const int nt = (seg == 0) ? nt0 : nt1;
    const int kv0 = it * 128;

    // ---- top gate: K(u) complete everywhere; V(u) may still fly ----
    asm volatile("s_waitcnt vmcnt(4)" ::: "memory");
    __builtin_amdgcn_s_barrier();
    __builtin_amdgcn_sched_barrier(0);

    if (it == 0) {   // segment init: Q fragments (16 rows/wave) + state reset
      q0w = jbs[seg] * 128 + wid * 16;
#pragma unroll
      for (int kq = 0; kq < 4; ++kq)
        qf[kq] = *(const bf16x8*)(qh + (size_t)(q0w + rowA) * 128 + kq * 32 + kgrp);
#pragma unroll
      for (int dn = 0; dn < 8; ++dn) o[dn] = z4;
#pragma unroll
      for (int r2 = 0; r2 < 4; ++r2) { mprev[r2] = -1e30f; lsum[r2] = 0.f; }
    }

    // ---- S = Q K^T over 128 kv (swizzled LDS) ----
    f32x4 s[8];
#pragma unroll
    for (int n = 0; n < 8; ++n) s[n] = z4;
    __builtin_amdgcn_s_setprio(1);
#pragma unroll
    for (int kq = 0; kq < 4; ++kq) {
#pragma unroll
      for (int n = 0; n < 8; ++n) {
        int row = n * 16 + rowA;
        int ch  = (kq * 4 + kg) ^ (row & 7);
        bf16x8 bkk = *(const bf16x8*)&lds[row * 128 + ch * 8];
        s[n] = __builtin_amdgcn_mfma_f32_16x16x32_bf16(qf[kq], bkk, s[n], 0, 0, 0);
      }
    }
    __builtin_amdgcn_s_setprio(0);

    // ---- mid gate: V(u) drained + K reads done -> P region free, V visible
    asm volatile("s_waitcnt vmcnt(0) lgkmcnt(0)" ::: "memory");
    __builtin_amdgcn_s_barrier();
    __builtin_amdgcn_sched_barrier(0);

    // ---- causal mask (only the diagonal tile) ----
    if (kv0 + 127 > q0w) {
#pragma unroll
      for (int n = 0; n < 8; ++n)
#pragma unroll
        for (int r2 = 0; r2 < 4; ++r2) {
          int qg = q0w + rgrp + r2;
          int kgl = kv0 + n * 16 + rowA;
          if (kgl > qg) s[n][r2] = -1e30f;
        }
    }

    // ---- online softmax (base-2), step-major trees, defer-max ----
    float tmax[4];
#pragma unroll
    for (int r2 = 0; r2 < 4; ++r2) {
      float t = s[0][r2];
#pragma unroll
      for (int n = 1; n < 8; ++n) t = fmaxf(t, s[n][r2]);
      tmax[r2] = t;
    }
#pragma unroll
    for (int stp = 1; stp <= 8; stp <<= 1)
#pragma unroll
      for (int r2 = 0; r2 < 4; ++r2)
        tmax[r2] = fmaxf(tmax[r2], __shfl_xor(tmax[r2], stp));

    bool ok = true;
#pragma unroll
    for (int r2 = 0; r2 < 4; ++r2) ok = ok && (tmax[r2] <= mprev[r2] + 8.0f);
    const bool skip = __all(ok ? 1 : 0);

    float mnew[4], psum[4];
#pragma unroll
    for (int r2 = 0; r2 < 4; ++r2) {
      mnew[r2] = skip ? mprev[r2] : fmaxf(mprev[r2], tmax[r2]);
      float ps = 0.f;
#pragma unroll
      for (int n = 0; n < 8; ++n) {
        float pv = exp2f(s[n][r2] - mnew[r2]);
        s[n][r2] = pv;
        ps += pv;
      }
      psum[r2] = ps;
    }
#pragma unroll
    for (int stp = 1; stp <= 8; stp <<= 1)
#pragma unroll
      for (int r2 = 0; r2 < 4; ++r2)
        psum[r2] += __shfl_xor(psum[r2], stp);

#pragma unroll
    for (int r2 = 0; r2 < 4; ++r2) {
      if (skip) {
        lsum[r2] += psum[r2];
      } else {
        float alpha = exp2f(mprev[r2] - mnew[r2]);
        lsum[r2] = lsum[r2] * alpha + psum[r2];
        mprev[r2] = mnew[r2];
#pragma unroll
        for (int dn = 0; dn < 8; ++dn) o[dn][r2] *= alpha;
      }
    }

    // ---- PV in two passes; P [16][64]/wave overlays Kbuf[0..8192 ush) ----
    unsigned short* Pw = &lds[wid * 1024];
    const unsigned short* Vb = &lds[16384];
#pragma unroll
    for (int pass = 0; pass < 2; ++pass) {
#pragma unroll
      for (int nl = 0; nl < 4; ++nl)
#pragma unroll
        for (int r2 = 0; r2 < 4; ++r2) {
          int row = rgrp + r2;
          int col = nl * 16 + rowA;
          Pw[row * 64 + (col ^ ((row & 7) << 3))] = f2bf(s[pass * 4 + nl][r2]);
        }
      // per-wave DS ordering: compiler inserts lgkmcnt waits before reads
      __builtin_amdgcn_s_setprio(1);
#pragma unroll
      for (int kkl = 0; kkl < 2; ++kkl) {
        const int kk = pass * 2 + kkl;
        bf16x8 pa;
        {
          int row = rowA;
          int col0 = kkl * 32 + kgrp;
          pa = *(const bf16x8*)&Pw[row * 64 + (col0 ^ ((row & 7) << 3))];
        }
#pragma unroll
        for (int dn = 0; dn < 8; ++dn) {
          int row = dn * 16 + rowA;
          int ch  = (kk * 4 + kg) ^ (row & 7);
          bf16x8 vb = *(const bf16x8*)&Vb[row * 128 + ch * 8];
          o[dn] = __builtin_amdgcn_mfma_f32_16x16x32_bf16(pa, vb, o[dn], 0, 0, 0);
        }
      }
      __builtin_amdgcn_s_setprio(0);
    }

    // ---- segment epilogue: normalize and write ----
    if (it == nt - 1) {
      float rinv[4];
#pragma unroll
      for (int r2 = 0; r2 < 4; ++r2) rinv[r2] = 1.0f / lsum[r2];
#pragma unroll
      for (int dn = 0; dn < 8; ++dn)
#pragma unroll
        for (int r2 = 0; r2 < 4; ++r2) {
          float v = o[dn][r2] * rinv[r2];
          int t = q0w + rgrp + r2;
          int col = h * 128 + dn * 16 + rowA;
          obt[((size_t)b * 2048 + t) * 2048 + col] = f2bf(v);
        }
    }

    __syncthreads(); // drains everything (vmcnt0+lgkmcnt0); buffers reusable

    // ---- stage next K and V (K first = oldest; gated at next top) ----
    if (u + 1 < total) {
      const int itn = (u + 1 >= nt0) ? (u + 1 - nt0) : (u + 1);
      STAGE_K(itn * 128);
      STAGE_V(itn * 128);
    }

    ++it;
    if (seg == 0 && it == nt0) { seg = 1; it = 0; }
  }
}

// ---- host launch -----------------------------------------------------------
extern "C" void kernel_launch(void* const* d_in, const int* in_sizes, int n_in,
                              void* d_out, int out_size, void* d_ws, size_t ws_size,
                              hipStream_t stream) {
  const float* x  = (const float*)d_in[0];
  const float* Wq = (const float*)d_in[2];
  const float* Wk = (const float*)d_in[3];
  const float* Wv = (const float*)d_in[4];
  const float* Wo = (const float*)d_in[5];
  float* out = (float*)d_out;

  char* ws = (char*)d_ws;
  unsigned short* xb  = (unsigned short*)(ws + 0);
  unsigned short* wqb = (unsigned short*)(ws + 16777216);
  unsigned short* wkb = (unsigned short*)(ws + 25165824);
  unsigned short* wvb = (unsigned short*)(ws + 33554432);
  unsigned short* wob = (unsigned short*)(ws + 41943040);
  unsigned short* qb  = (unsigned short*)(ws + 50331648);
  unsigned short* kb  = (unsigned short*)(ws + 67108864);
  unsigned short* vtb = (unsigned short*)(ws + 83886080);
  unsigned short* obt = (unsigned short*)(ws + 100663296);
  float* ct = (float*)(ws + 117440512);
  float* st = (float*)(ws + 117964800);

  k_cvt5<<<2048, 256, 0, stream>>>(x, Wq, Wk, Wv, Wo, xb, wqb, wkb, wvb, wob, ct, st);
  dim3 gq(48, 16); // merged QKV: 6144/128 x 4096/256 = 768 blocks = 3 even rounds
  k_gemm256n128<1><<<gq, 512, 0, stream>>>(xb, wqb, wkb, wvb, nullptr, qb, kb, vtb);
  k_rope<<<16384, 256, 0, stream>>>(qb, kb, ct, st);
  k_flash<<<256, 512, 0, stream>>>(qb, kb, vtb, obt);
  dim3 go(16, 16); // Wo: 256 blocks = 1 full-chip round
  k_gemm256n128<0><<<go, 512, 0, stream>>>(obt, wob, nullptr, nullptr, out, nullptr, nullptr, nullptr);
}

// Round 26
// 268.985 us; speedup vs baseline: 1.0085x; 1.0020x over previous
//
#include <hip/hip_runtime.h>
#include <stdint.h>

#define AS1 __attribute__((address_space(1)))
#define AS3 __attribute__((address_space(3)))

using bf16x8 = __attribute__((ext_vector_type(8))) short;
using f32x4  = __attribute__((ext_vector_type(4))) float;

// ---- helpers -------------------------------------------------------------
__device__ __forceinline__ unsigned short f2bf(float f) {
  union { float f; unsigned u; } v; v.f = f;
  return (unsigned short)((v.u + 0x7FFFu + ((v.u >> 16) & 1u)) >> 16); // RNE
}
__device__ __forceinline__ float bf2f(unsigned short h) {
  union { unsigned u; float f; } v; v.u = ((unsigned)h) << 16;
  return v.f;
}
// async global->LDS, 16B per lane; lds dest must be wave-uniform base (HW adds lane*16)
__device__ __forceinline__ void gload_lds16(const void* g, void* l) {
  __builtin_amdgcn_global_load_lds((AS1 const void*)g, (AS3 void*)l, 16, 0, 0);
}

// ---- fused fp32->bf16 convert (x + 4 weights) + RoPE tables, one launch ----
__global__ void k_cvt5(const float* __restrict__ x,  const float* __restrict__ wq,
                       const float* __restrict__ wk, const float* __restrict__ wv,
                       const float* __restrict__ wo,
                       unsigned short* __restrict__ xb,  unsigned short* __restrict__ wqb,
                       unsigned short* __restrict__ wkb, unsigned short* __restrict__ wvb,
                       unsigned short* __restrict__ wob,
                       float* __restrict__ ct, float* __restrict__ st) {
  int idx = blockIdx.x * blockDim.x + threadIdx.x;
  int stride = gridDim.x * blockDim.x;
  for (int i = idx; i < 6422528; i += stride) {
    if (i >= 6291456) { // rope tables
      int j = i - 6291456;
      int t = j >> 6, fi = j & 63;
      float invf = exp2f(-(float)fi * (13.287712379549449f / 64.0f));
      float a = (float)t * invf;
      ct[j] = cosf(a);
      st[j] = sinf(a);
      continue;
    }
    const float* src; unsigned short* dst; int off;
    if (i < 2097152) { src = x; dst = xb; off = i; }
    else {
      int j = i - 2097152;
      int w = j >> 20;            // 1,048,576 float4 per weight
      off = j & 1048575;
      src = (w == 0) ? wq : (w == 1) ? wk : (w == 2) ? wv : wo;
      dst = (w == 0) ? wqb : (w == 1) ? wkb : (w == 2) ? wvb : wob;
    }
    float4 f = ((const float4*)src)[off];
    ushort4 o;
    o.x = f2bf(f.x); o.y = f2bf(f.y); o.z = f2bf(f.z); o.w = f2bf(f.w);
    ((ushort4*)dst)[off] = o;
  }
}

// ---- 256x128 GEMM, counted-vmcnt pipeline + FUSED RoPE epilogue ------------
// r23/r25's verified kernel; for MODE 1 w<2 the epilogue now applies RoPE
// in-kernel: BN=128 => each block covers exactly ONE head (d spans 0..127),
// so pair partners (d, d+64) are both in-block (wn=0 holds d<64, wn=1 d>=64).
// acc is staged as bf16 [256][128] into the now-dead LDS (64KB <= 96KB) —
// bit-identical numerics to the old separate k_rope pass (which also read
// bf16-rounded GEMM output). Q additionally scaled by (1/sqrt(128))*log2(e).
// Saves the k_rope launch + its ~64MB round-trip (~10us).
// MODE 0: f32 out [M,2048] (Wo, grid 16x16).  MODE 1: QKV (grid 48x16).
template <int MODE>
__global__ __launch_bounds__(512, 2) void k_gemm256n128(
    const unsigned short* __restrict__ Ag,
    const unsigned short* __restrict__ B0,
    const unsigned short* __restrict__ B1,
    const unsigned short* __restrict__ B2,
    float* __restrict__ outF,
    unsigned short* __restrict__ outQ,
    unsigned short* __restrict__ outK,
    unsigned short* __restrict__ outVT,
    const float* __restrict__ ctg,
    const float* __restrict__ stg) {
  // ush: A dbuf [2][16384] @0 | B dbuf [2][8192] @32768   (= 96 KiB)
  __shared__ __align__(16) unsigned short lds[49152];

  const int tid = threadIdx.x;
  const int wid = tid >> 6, lane = tid & 63;
  const int wm = wid >> 1, wn = wid & 1;      // 4M x 2N wave grid
  const int rowA = lane & 15, kg = lane >> 4;
  const int rgrp = kg * 4;
  const int swz = rowA & 7;

  const int m0 = blockIdx.y * 256;
  const int n0g = blockIdx.x * 128;
  int w, n0;
  const unsigned short* Bg;
  if (MODE == 0) { w = 0; n0 = n0g; Bg = B0; }
  else { w = n0g >> 11; n0 = n0g & 2047; Bg = (w == 0) ? B0 : (w == 1) ? B1 : B2; }

  const int aBase = wm * 4096 + rowA * 64;
  const int bBase = wn * 4096 + rowA * 64;
  const int ch0 = (kg ^ swz) * 8;
  const int ch1 = ((4 + kg) ^ swz) * 8;

  const int grow = wid * 8 + (lane >> 3);
  const int gch  = ((lane & 7) ^ ((lane >> 3) & 7)) * 8;
  const int sdst = wid * 512;

  auto SA = [&](int dst, int t1, int c4) {
    gload_lds16(Ag + (size_t)(m0 + c4 * 64 + grow) * 2048 + t1 * 64 + gch,
                (void*)&lds[dst * 16384 + c4 * 4096 + sdst]);
  };
  auto SB = [&](int dst, int t1, int c2) {
    gload_lds16(Bg + (size_t)(n0 + c2 * 64 + grow) * 2048 + t1 * 64 + gch,
                (void*)&lds[32768 + dst * 8192 + c2 * 4096 + sdst]);
  };
  auto STAGE = [&](int dst, int t1) { // 6 gloads: the per-tile unit
    SA(dst, t1, 0); SA(dst, t1, 1); SA(dst, t1, 2); SA(dst, t1, 3);
    SB(dst, t1, 0); SB(dst, t1, 1);
  };

  f32x4 acc[4][4];
  const f32x4 z4 = {0.f, 0.f, 0.f, 0.f};
#pragma unroll
  for (int i = 0; i < 4; ++i)
#pragma unroll
    for (int j = 0; j < 4; ++j) acc[i][j] = z4;

  // prologue: stage t0 -> buf0 and t1 -> buf1; gate t0 (t1's 6 stay in flight)
  STAGE(0, 0);
  STAGE(1, 1);
  asm volatile("s_waitcnt vmcnt(6)" ::: "memory");
  __builtin_amdgcn_s_barrier();
  __builtin_amdgcn_sched_barrier(0);

  for (int t = 0; t < 32; ++t) {
    const int c = t & 1;
    const int cA = c * 16384, cB = 32768 + c * 8192;
    bf16x8 af[4], bk[4];

    // ---- compute K-tile t from buf c (both kk halves, 32 MFMA) ----
    __builtin_amdgcn_s_setprio(1);
#pragma unroll
    for (int i = 0; i < 4; ++i) af[i] = *(const bf16x8*)&lds[cA + aBase + i * 1024 + ch0];
#pragma unroll
    for (int j = 0; j < 4; ++j) bk[j] = *(const bf16x8*)&lds[cB + bBase + j * 1024 + ch0];
#pragma unroll
    for (int i = 0; i < 4; ++i)
#pragma unroll
      for (int j = 0; j < 4; ++j)
        acc[i][j] = __builtin_amdgcn_mfma_f32_16x16x32_bf16(af[i], bk[j], acc[i][j], 0, 0, 0);
#pragma unroll
    for (int i = 0; i < 4; ++i) af[i] = *(const bf16x8*)&lds[cA + aBase + i * 1024 + ch1];
#pragma unroll
    for (int j = 0; j < 4; ++j) bk[j] = *(const bf16x8*)&lds[cB + bBase + j * 1024 + ch1];
#pragma unroll
    for (int i = 0; i < 4; ++i)
#pragma unroll
      for (int j = 0; j < 4; ++j)
        acc[i][j] = __builtin_amdgcn_mfma_f32_16x16x32_bf16(af[i], bk[j], acc[i][j], 0, 0, 0);
    __builtin_amdgcn_s_setprio(0);

    if (t < 31) {
      // all waves done reading buf c -> safe to overwrite
      asm volatile("s_waitcnt lgkmcnt(0)" ::: "memory");
      __builtin_amdgcn_s_barrier();
      __builtin_amdgcn_sched_barrier(0);
      if (t + 2 < 32) {
        STAGE(c, t + 2);                                  // into freed buf c
        asm volatile("s_waitcnt vmcnt(6)" ::: "memory");  // t+1 retired
      } else {
        asm volatile("s_waitcnt vmcnt(0)" ::: "memory");  // tail: drain t+1
      }
      __builtin_amdgcn_s_barrier();                       // publish t+1
      __builtin_amdgcn_sched_barrier(0);
    }
  }

  // ---- epilogue ----
  if (MODE == 1 && w < 2) {
    // fused RoPE: stage acc as bf16 [256][128] in LDS, pair (d, d+64)
    __syncthreads(); // all waves past their final tile-buffer reads
    unsigned short* Eb = lds;
#pragma unroll
    for (int i = 0; i < 4; ++i)
#pragma unroll
      for (int j = 0; j < 4; ++j)
#pragma unroll
        for (int r = 0; r < 4; ++r) {
          int ml = wm * 64 + i * 16 + rgrp + r;
          int dl = wn * 64 + j * 16 + rowA;
          Eb[ml * 128 + dl] = f2bf(acc[i][j][r]);
        }
    __syncthreads();
    unsigned short* C = w ? outK : outQ;
    const int h = n0 >> 7;            // BN=128: exactly one head per block
    const int d = tid & 63;
    const int mg0 = (tid >> 6) * 32;  // 8 groups x 32 rows
    const float SC2 = 0.12751659974141322f; // (1/sqrt(128))*log2(e), Q only
    for (int mi = 0; mi < 32; ++mi) {
      int m = mg0 + mi;
      int gm = m0 + m;
      int t = gm & 2047, b = gm >> 11;
      float x1 = bf2f(Eb[m * 128 + d]);
      float x2 = bf2f(Eb[m * 128 + d + 64]);
      float c = ctg[t * 64 + d], s = stg[t * 64 + d];
      float y1 = x1 * c - x2 * s;
      float y2 = x2 * c + x1 * s;
      if (w == 0) { y1 *= SC2; y2 *= SC2; }
      size_t base = ((size_t)(b * 16 + h) * 2048 + t) * 128;
      C[base + d]      = f2bf(y1);
      C[base + d + 64] = f2bf(y2);
    }
  } else {
#pragma unroll
    for (int i = 0; i < 4; ++i) {
#pragma unroll
      for (int j = 0; j < 4; ++j) {
        const int gm0 = m0 + wm * 64 + i * 16 + rgrp;
        const int gn  = n0 + wn * 64 + j * 16 + rowA;
        if (MODE == 0) {
#pragma unroll
          for (int r = 0; r < 4; ++r)
            outF[(size_t)(gm0 + r) * 2048 + gn] = acc[i][j][r];
        } else { // w == 2: transposed V
          int h = gn >> 7, dd = gn & 127;
          int b = gm0 >> 11, tt = gm0 & 2047;
          ushort4 pk;
          pk.x = f2bf(acc[i][j][0]); pk.y = f2bf(acc[i][j][1]);
          pk.z = f2bf(acc[i][j][2]); pk.w = f2bf(acc[i][j][3]);
          *(ushort4*)&outVT[(((size_t)(b * 16 + h)) * 128 + dd) * 2048 + tt] = pk;
        }
      }
    }
  }
}

// ---- flash attention fwd: EXACT r21 kernel (8 waves x 16 q-rows, ~100us) ---
__global__ __launch_bounds__(512) void k_flash(const unsigned short* __restrict__ q,
                                               const unsigned short* __restrict__ k,
                                               const unsigned short* __restrict__ vt,
                                               unsigned short* __restrict__ obt) {
  // ush: K[16384] @0 (P overlays [0,8192)) | V[16384] @16384   (= 64 KiB)
  __shared__ __align__(16) unsigned short lds[32768];

  const int tid = threadIdx.x;
  const int wid = tid >> 6, lane = tid & 63;   // wid 0..7
  const int rowA = lane & 15, kg = lane >> 4;
  const int kgrp = kg * 8, rgrp = kg * 4;

  const int bid = blockIdx.x;          // 0..255
  const int xcd = bid & 7;             // round-robin XCD dispatch (perf-only)
  const int r0  = bid >> 3;            // 0..31
  const int bh  = xcd * 4 + (r0 & 3);  // 4 heads per XCD chunk
  const int p   = r0 >> 2;             // 0..7
  const int b = bh >> 4, h = bh & 15;

  const int jbs[2] = {15 - p, p};      // heavy segment first
  const int nt0 = jbs[0] + 1, nt1 = jbs[1] + 1;
  const int total = nt0 + nt1;         // = 17 for every block

  const unsigned short* qh  = q  + (size_t)bh * 2048 * 128;
  const unsigned short* kh  = k  + (size_t)bh * 2048 * 128;
  const unsigned short* vth = vt + (size_t)bh * 128 * 2048;

  const int srow4 = wid * 4 + (lane >> 4); // 0..31
  auto STAGE_K = [&](int kv0) {
#pragma unroll
    for (int c = 0; c < 4; ++c) {
      int row = c * 32 + srow4;
      int ch  = (lane & 15) ^ (row & 7);
      gload_lds16(kh + (size_t)(kv0 + row) * 128 + ch * 8,
                  (void*)&lds[(c * 32 + wid * 4) * 128]);
    }
  };
  auto STAGE_V = [&](int kv0) {
#pragma unroll
    for (int c = 0; c < 4; ++c) {
      int row = c * 32 + srow4;            // d-dim row
      int ch  = (lane & 15) ^ (row & 7);
      gload_lds16(vth + (size_t)row * 2048 + kv0 + ch * 8,
                  (void*)&lds[16384 + (c * 32 + wid * 4) * 128]);
    }
  };

  const f32x4 z4 = {0.f, 0.f, 0.f, 0.f};
  bf16x8 qf[4];
  f32x4 o[8];
  float mprev[4], lsum[4];
  int q0w = 0;

  int seg = 0, it = 0;
  STAGE_K(0);   // 4 oldest vmem ops/thread
  STAGE_V(0);   // 4 newest

  for (int u = 0; u < total; ++u) {
    const int nt = (seg == 0) ? nt0 : nt1;
    const int kv0 = it * 128;

    // ---- top gate: K(u) complete everywhere; V(u) may still fly ----
    asm volatile("s_waitcnt vmcnt(4)" ::: "memory");
    __builtin_amdgcn_s_barrier();
    __builtin_amdgcn_sched_barrier(0);

    if (it == 0) {   // segment init: Q fragments (16 rows/wave) + state reset
      q0w = jbs[seg] * 128 + wid * 16;
#pragma unroll
      for (int kq = 0; kq < 4; ++kq)
        qf[kq] = *(const bf16x8*)(qh + (size_t)(q0w + rowA) * 128 + kq * 32 + kgrp);
#pragma unroll
      for (int dn = 0; dn < 8; ++dn) o[dn] = z4;
#pragma unroll
      for (int r2 = 0; r2 < 4; ++r2) { mprev[r2] = -1e30f; lsum[r2] = 0.f; }
    }

    // ---- S = Q K^T over 128 kv (swizzled LDS) ----
    f32x4 s[8];
#pragma unroll
    for (int n = 0; n < 8; ++n) s[n] = z4;
    __builtin_amdgcn_s_setprio(1);
#pragma unroll
    for (int kq = 0; kq < 4; ++kq) {
#pragma unroll
      for (int n = 0; n < 8; ++n) {
        int row = n * 16 + rowA;
        int ch  = (kq * 4 + kg) ^ (row & 7);
        bf16x8 bkk = *(const bf16x8*)&lds[row * 128 + ch * 8];
        s[n] = __builtin_amdgcn_mfma_f32_16x16x32_bf16(qf[kq], bkk, s[n], 0, 0, 0);
      }
    }
    __builtin_amdgcn_s_setprio(0);

    // ---- mid gate: V(u) drained + K reads done -> P region free, V visible
    asm volatile("s_waitcnt vmcnt(0) lgkmcnt(0)" ::: "memory");
    __builtin_amdgcn_s_barrier();
    __builtin_amdgcn_sched_barrier(0);

    // ---- causal mask (only the diagonal tile) ----
    if (kv0 + 127 > q0w) {
#pragma unroll
      for (int n = 0; n < 8; ++n)
#pragma unroll
        for (int r2 = 0; r2 < 4; ++r2) {
          int qg = q0w + rgrp + r2;
          int kgl = kv0 + n * 16 + rowA;
          if (kgl > qg) s[n][r2] = -1e30f;
        }
    }

    // ---- online softmax (base-2), step-major trees, defer-max ----
    float tmax[4];
#pragma unroll
    for (int r2 = 0; r2 < 4; ++r2) {
      float t = s[0][r2];
#pragma unroll
      for (int n = 1; n < 8; ++n) t = fmaxf(t, s[n][r2]);
      tmax[r2] = t;
    }
#pragma unroll
    for (int stp = 1; stp <= 8; stp <<= 1)
#pragma unroll
      for (int r2 = 0; r2 < 4; ++r2)
        tmax[r2] = fmaxf(tmax[r2], __shfl_xor(tmax[r2], stp));

    bool ok = true;
#pragma unroll
    for (int r2 = 0; r2 < 4; ++r2) ok = ok && (tmax[r2] <= mprev[r2] + 8.0f);
    const bool skip = __all(ok ? 1 : 0);

    float mnew[4], psum[4];
#pragma unroll
    for (int r2 = 0; r2 < 4; ++r2) {
      mnew[r2] = skip ? mprev[r2] : fmaxf(mprev[r2], tmax[r2]);
      float ps = 0.f;
#pragma unroll
      for (int n = 0; n < 8; ++n) {
        float pv = exp2f(s[n][r2] - mnew[r2]);
        s[n][r2] = pv;
        ps += pv;
      }
      psum[r2] = ps;
    }
#pragma unroll
    for (int stp = 1; stp <= 8; stp <<= 1)
#pragma unroll
      for (int r2 = 0; r2 < 4; ++r2)
        psum[r2] += __shfl_xor(psum[r2], stp);

#pragma unroll
    for (int r2 = 0; r2 < 4; ++r2) {
      if (skip) {
        lsum[r2] += psum[r2];
      } else {
        float alpha = exp2f(mprev[r2] - mnew[r2]);
        lsum[r2] = lsum[r2] * alpha + psum[r2];
        mprev[r2] = mnew[r2];
#pragma unroll
        for (int dn = 0; dn < 8; ++dn) o[dn][r2] *= alpha;
      }
    }

    // ---- PV in two passes; P [16][64]/wave overlays Kbuf[0..8192 ush) ----
    unsigned short* Pw = &lds[wid * 1024];
    const unsigned short* Vb = &lds[16384];
#pragma unroll
    for (int pass = 0; pass < 2; ++pass) {
#pragma unroll
      for (int nl = 0; nl < 4; ++nl)
#pragma unroll
        for (int r2 = 0; r2 < 4; ++r2) {
          int row = rgrp + r2;
          int col = nl * 16 + rowA;
          Pw[row * 64 + (col ^ ((row & 7) << 3))] = f2bf(s[pass * 4 + nl][r2]);
        }
      // per-wave DS ordering: compiler inserts lgkmcnt waits before reads
      __builtin_amdgcn_s_setprio(1);
#pragma unroll
      for (int kkl = 0; kkl < 2; ++kkl) {
        const int kk = pass * 2 + kkl;
        bf16x8 pa;
        {
          int row = rowA;
          int col0 = kkl * 32 + kgrp;
          pa = *(const bf16x8*)&Pw[row * 64 + (col0 ^ ((row & 7) << 3))];
        }
#pragma unroll
        for (int dn = 0; dn < 8; ++dn) {
          int row = dn * 16 + rowA;
          int ch  = (kk * 4 + kg) ^ (row & 7);
          bf16x8 vb = *(const bf16x8*)&Vb[row * 128 + ch * 8];
          o[dn] = __builtin_amdgcn_mfma_f32_16x16x32_bf16(pa, vb, o[dn], 0, 0, 0);
        }
      }
      __builtin_amdgcn_s_setprio(0);
    }

    // ---- segment epilogue: normalize and write ----
    if (it == nt - 1) {
      float rinv[4];
#pragma unroll
      for (int r2 = 0; r2 < 4; ++r2) rinv[r2] = 1.0f / lsum[r2];
#pragma unroll
      for (int dn = 0; dn < 8; ++dn)
#pragma unroll
        for (int r2 = 0; r2 < 4; ++r2) {
          float v = o[dn][r2] * rinv[r2];
          int t = q0w + rgrp + r2;
          int col = h * 128 + dn * 16 + rowA;
          obt[((size_t)b * 2048 + t) * 2048 + col] = f2bf(v);
        }
    }

    __syncthreads(); // drains everything (vmcnt0+lgkmcnt0); buffers reusable

    // ---- stage next K and V (K first = oldest; gated at next top) ----
    if (u + 1 < total) {
      const int itn = (u + 1 >= nt0) ? (u + 1 - nt0) : (u + 1);
      STAGE_K(itn * 128);
      STAGE_V(itn * 128);
    }

    ++it;
    if (seg == 0 && it == nt0) { seg = 1; it = 0; }
  }
}

// ---- host launch -----------------------------------------------------------
extern "C" void kernel_launch(void* const* d_in, const int* in_sizes, int n_in,
                              void* d_out, int out_size, void* d_ws, size_t ws_size,
                              hipStream_t stream) {
  const float* x  = (const float*)d_in[0];
  const float* Wq = (const float*)d_in[2];
  const float* Wk = (const float*)d_in[3];
  const float* Wv = (const float*)d_in[4];
  const float* Wo = (const float*)d_in[5];
  float* out = (float*)d_out;

  char* ws = (char*)d_ws;
  unsigned short* xb  = (unsigned short*)(ws + 0);
  unsigned short* wqb = (unsigned short*)(ws + 16777216);
  unsigned short* wkb = (unsigned short*)(ws + 25165824);
  unsigned short* wvb = (unsigned short*)(ws + 33554432);
  unsigned short* wob = (unsigned short*)(ws + 41943040);
  unsigned short* qb  = (unsigned short*)(ws + 50331648);
  unsigned short* kb  = (unsigned short*)(ws + 67108864);
  unsigned short* vtb = (unsigned short*)(ws + 83886080);
  unsigned short* obt = (unsigned short*)(ws + 100663296);
  float* ct = (float*)(ws + 117440512);
  float* st = (float*)(ws + 117964800);

  k_cvt5<<<2048, 256, 0, stream>>>(x, Wq, Wk, Wv, Wo, xb, wqb, wkb, wvb, wob, ct, st);
  dim3 gq(48, 16); // merged QKV: 768 blocks = 3 even rounds; RoPE fused in epilogue
  k_gemm256n128<1><<<gq, 512, 0, stream>>>(xb, wqb, wkb, wvb, nullptr, qb, kb, vtb, ct, st);
  k_flash<<<256, 512, 0, stream>>>(qb, kb, vtb, obt);
  dim3 go(16, 16); // Wo: 256 blocks = 1 full-chip round
  k_gemm256n128<0><<<go, 512, 0, stream>>>(obt, wob, nullptr, nullptr, out, nullptr, nullptr, nullptr, nullptr, nullptr);
}

// Round 27
// 259.991 us; speedup vs baseline: 1.0434x; 1.0346x over previous
//
#include <hip/hip_runtime.h>
#include <stdint.h>

#define AS1 __attribute__((address_space(1)))
#define AS3 __attribute__((address_space(3)))

using bf16x8 = __attribute__((ext_vector_type(8))) short;
using f32x4  = __attribute__((ext_vector_type(4))) float;

// ---- helpers -------------------------------------------------------------
__device__ __forceinline__ unsigned short f2bf(float f) {
  union { float f; unsigned u; } v; v.f = f;
  return (unsigned short)((v.u + 0x7FFFu + ((v.u >> 16) & 1u)) >> 16); // RNE
}
__device__ __forceinline__ float bf2f(unsigned short h) {
  union { unsigned u; float f; } v; v.u = ((unsigned)h) << 16;
  return v.f;
}
// async global->LDS, 16B per lane; lds dest must be wave-uniform base (HW adds lane*16)
__device__ __forceinline__ void gload_lds16(const void* g, void* l) {
  __builtin_amdgcn_global_load_lds((AS1 const void*)g, (AS3 void*)l, 16, 0, 0);
}

// ---- fused fp32->bf16 convert (x + 4 weights) + RoPE tables, one launch ----
__global__ void k_cvt5(const float* __restrict__ x,  const float* __restrict__ wq,
                       const float* __restrict__ wk, const float* __restrict__ wv,
                       const float* __restrict__ wo,
                       unsigned short* __restrict__ xb,  unsigned short* __restrict__ wqb,
                       unsigned short* __restrict__ wkb, unsigned short* __restrict__ wvb,
                       unsigned short* __restrict__ wob,
                       float* __restrict__ ct, float* __restrict__ st) {
  int idx = blockIdx.x * blockDim.x + threadIdx.x;
  int stride = gridDim.x * blockDim.x;
  for (int i = idx; i < 6422528; i += stride) {
    if (i >= 6291456) { // rope tables
      int j = i - 6291456;
      int t = j >> 6, fi = j & 63;
      float invf = exp2f(-(float)fi * (13.287712379549449f / 64.0f));
      float a = (float)t * invf;
      ct[j] = cosf(a);
      st[j] = sinf(a);
      continue;
    }
    const float* src; unsigned short* dst; int off;
    if (i < 2097152) { src = x; dst = xb; off = i; }
    else {
      int j = i - 2097152;
      int w = j >> 20;            // 1,048,576 float4 per weight
      off = j & 1048575;
      src = (w == 0) ? wq : (w == 1) ? wk : (w == 2) ? wv : wo;
      dst = (w == 0) ? wqb : (w == 1) ? wkb : (w == 2) ? wvb : wob;
    }
    float4 f = ((const float4*)src)[off];
    ushort4 o;
    o.x = f2bf(f.x); o.y = f2bf(f.y); o.z = f2bf(f.z); o.w = f2bf(f.w);
    ((ushort4*)dst)[off] = o;
  }
}

// ---- 256x128 GEMM, counted-vmcnt pipeline + FUSED RoPE epilogue (vec) ------
// r26's kernel with the RoPE epilogue VECTORIZED (r26's scalar loop cost
// +12.6us; G13: 2B scalar stores). Thread owns d0=(tid&15)*4, group tid>>4
// owns 8 rows: 8 iters x {2 ushort4 LDS reads, 2 float4 table loads, 2
// ushort4 global stores}. Numerics bit-identical (same bf16 round points).
// MODE 0: f32 out [M,2048] (Wo, grid 16x16).  MODE 1: QKV (grid 48x16).
template <int MODE>
__global__ __launch_bounds__(512, 2) void k_gemm256n128(
    const unsigned short* __restrict__ Ag,
    const unsigned short* __restrict__ B0,
    const unsigned short* __restrict__ B1,
    const unsigned short* __restrict__ B2,
    float* __restrict__ outF,
    unsigned short* __restrict__ outQ,
    unsigned short* __restrict__ outK,
    unsigned short* __restrict__ outVT,
    const float* __restrict__ ctg,
    const float* __restrict__ stg) {
  // ush: A dbuf [2][16384] @0 | B dbuf [2][8192] @32768   (= 96 KiB)
  __shared__ __align__(16) unsigned short lds[49152];

  const int tid = threadIdx.x;
  const int wid = tid >> 6, lane = tid & 63;
  const int wm = wid >> 1, wn = wid & 1;      // 4M x 2N wave grid
  const int rowA = lane & 15, kg = lane >> 4;
  const int rgrp = kg * 4;
  const int swz = rowA & 7;

  const int m0 = blockIdx.y * 256;
  const int n0g = blockIdx.x * 128;
  int w, n0;
  const unsigned short* Bg;
  if (MODE == 0) { w = 0; n0 = n0g; Bg = B0; }
  else { w = n0g >> 11; n0 = n0g & 2047; Bg = (w == 0) ? B0 : (w == 1) ? B1 : B2; }

  const int aBase = wm * 4096 + rowA * 64;
  const int bBase = wn * 4096 + rowA * 64;
  const int ch0 = (kg ^ swz) * 8;
  const int ch1 = ((4 + kg) ^ swz) * 8;

  const int grow = wid * 8 + (lane >> 3);
  const int gch  = ((lane & 7) ^ ((lane >> 3) & 7)) * 8;
  const int sdst = wid * 512;

  auto SA = [&](int dst, int t1, int c4) {
    gload_lds16(Ag + (size_t)(m0 + c4 * 64 + grow) * 2048 + t1 * 64 + gch,
                (void*)&lds[dst * 16384 + c4 * 4096 + sdst]);
  };
  auto SB = [&](int dst, int t1, int c2) {
    gload_lds16(Bg + (size_t)(n0 + c2 * 64 + grow) * 2048 + t1 * 64 + gch,
                (void*)&lds[32768 + dst * 8192 + c2 * 4096 + sdst]);
  };
  auto STAGE = [&](int dst, int t1) { // 6 gloads: the per-tile unit
    SA(dst, t1, 0); SA(dst, t1, 1); SA(dst, t1, 2); SA(dst, t1, 3);
    SB(dst, t1, 0); SB(dst, t1, 1);
  };

  f32x4 acc[4][4];
  const f32x4 z4 = {0.f, 0.f, 0.f, 0.f};
#pragma unroll
  for (int i = 0; i < 4; ++i)
#pragma unroll
    for (int j = 0; j < 4; ++j) acc[i][j] = z4;

  // prologue: stage t0 -> buf0 and t1 -> buf1; gate t0 (t1's 6 stay in flight)
  STAGE(0, 0);
  STAGE(1, 1);
  asm volatile("s_waitcnt vmcnt(6)" ::: "memory");
  __builtin_amdgcn_s_barrier();
  __builtin_amdgcn_sched_barrier(0);

  for (int t = 0; t < 32; ++t) {
    const int c = t & 1;
    const int cA = c * 16384, cB = 32768 + c * 8192;
    bf16x8 af[4], bk[4];

    // ---- compute K-tile t from buf c (both kk halves, 32 MFMA) ----
    __builtin_amdgcn_s_setprio(1);
#pragma unroll
    for (int i = 0; i < 4; ++i) af[i] = *(const bf16x8*)&lds[cA + aBase + i * 1024 + ch0];
#pragma unroll
    for (int j = 0; j < 4; ++j) bk[j] = *(const bf16x8*)&lds[cB + bBase + j * 1024 + ch0];
#pragma unroll
    for (int i = 0; i < 4; ++i)
#pragma unroll
      for (int j = 0; j < 4; ++j)
        acc[i][j] = __builtin_amdgcn_mfma_f32_16x16x32_bf16(af[i], bk[j], acc[i][j], 0, 0, 0);
#pragma unroll
    for (int i = 0; i < 4; ++i) af[i] = *(const bf16x8*)&lds[cA + aBase + i * 1024 + ch1];
#pragma unroll
    for (int j = 0; j < 4; ++j) bk[j] = *(const bf16x8*)&lds[cB + bBase + j * 1024 + ch1];
#pragma unroll
    for (int i = 0; i < 4; ++i)
#pragma unroll
      for (int j = 0; j < 4; ++j)
        acc[i][j] = __builtin_amdgcn_mfma_f32_16x16x32_bf16(af[i], bk[j], acc[i][j], 0, 0, 0);
    __builtin_amdgcn_s_setprio(0);

    if (t < 31) {
      // all waves done reading buf c -> safe to overwrite
      asm volatile("s_waitcnt lgkmcnt(0)" ::: "memory");
      __builtin_amdgcn_s_barrier();
      __builtin_amdgcn_sched_barrier(0);
      if (t + 2 < 32) {
        STAGE(c, t + 2);                                  // into freed buf c
        asm volatile("s_waitcnt vmcnt(6)" ::: "memory");  // t+1 retired
      } else {
        asm volatile("s_waitcnt vmcnt(0)" ::: "memory");  // tail: drain t+1
      }
      __builtin_amdgcn_s_barrier();                       // publish t+1
      __builtin_amdgcn_sched_barrier(0);
    }
  }

  // ---- epilogue ----
  if (MODE == 1 && w < 2) {
    // fused RoPE: stage acc as bf16 [256][128] in LDS, pair (d, d+64)
    __syncthreads(); // all waves past their final tile-buffer reads
    unsigned short* Eb = lds;
#pragma unroll
    for (int i = 0; i < 4; ++i)
#pragma unroll
      for (int j = 0; j < 4; ++j)
#pragma unroll
        for (int r = 0; r < 4; ++r) {
          int ml = wm * 64 + i * 16 + rgrp + r;
          int dl = wn * 64 + j * 16 + rowA;
          Eb[ml * 128 + dl] = f2bf(acc[i][j][r]);
        }
    __syncthreads();
    unsigned short* C = w ? outK : outQ;
    const int h = n0 >> 7;            // BN=128: exactly one head per block
    const int d0 = (tid & 15) * 4;    // 4 consecutive d per thread
    const int g  = tid >> 4;          // 32 groups x 8 rows
    const float SC2 = 0.12751659974141322f; // (1/sqrt(128))*log2(e), Q only
#pragma unroll
    for (int mi = 0; mi < 8; ++mi) {
      int m = g * 8 + mi;
      int gm = m0 + m;
      int t = gm & 2047, b = gm >> 11;
      ushort4 a1 = *(const ushort4*)&Eb[m * 128 + d0];
      ushort4 a2 = *(const ushort4*)&Eb[m * 128 + d0 + 64];
      float4 cc = *(const float4*)&ctg[t * 64 + d0];
      float4 ss = *(const float4*)&stg[t * 64 + d0];
      float x1[4] = {bf2f(a1.x), bf2f(a1.y), bf2f(a1.z), bf2f(a1.w)};
      float x2[4] = {bf2f(a2.x), bf2f(a2.y), bf2f(a2.z), bf2f(a2.w)};
      float cv[4] = {cc.x, cc.y, cc.z, cc.w};
      float sv[4] = {ss.x, ss.y, ss.z, ss.w};
      ushort4 o1, o2;
      unsigned short* po1 = (unsigned short*)&o1;
      unsigned short* po2 = (unsigned short*)&o2;
#pragma unroll
      for (int e = 0; e < 4; ++e) {
        float y1 = x1[e] * cv[e] - x2[e] * sv[e];
        float y2 = x2[e] * cv[e] + x1[e] * sv[e];
        if (w == 0) { y1 *= SC2; y2 *= SC2; }
        po1[e] = f2bf(y1);
        po2[e] = f2bf(y2);
      }
      size_t base = ((size_t)(b * 16 + h) * 2048 + t) * 128;
      *(ushort4*)&C[base + d0]      = o1;
      *(ushort4*)&C[base + d0 + 64] = o2;
    }
  } else {
#pragma unroll
    for (int i = 0; i < 4; ++i) {
#pragma unroll
      for (int j = 0; j < 4; ++j) {
        const int gm0 = m0 + wm * 64 + i * 16 + rgrp;
        const int gn  = n0 + wn * 64 + j * 16 + rowA;
        if (MODE == 0) {
#pragma unroll
          for (int r = 0; r < 4; ++r)
            outF[(size_t)(gm0 + r) * 2048 + gn] = acc[i][j][r];
        } else { // w == 2: transposed V
          int h = gn >> 7, dd = gn & 127;
          int b = gm0 >> 11, tt = gm0 & 2047;
          ushort4 pk;
          pk.x = f2bf(acc[i][j][0]); pk.y = f2bf(acc[i][j][1]);
          pk.z = f2bf(acc[i][j][2]); pk.w = f2bf(acc[i][j][3]);
          *(ushort4*)&outVT[(((size_t)(b * 16 + h)) * 128 + dd) * 2048 + tt] = pk;
        }
      }
    }
  }
}

// ---- flash attention fwd: EXACT r21 kernel (8 waves x 16 q-rows, ~100us) ---
__global__ __launch_bounds__(512) void k_flash(const unsigned short* __restrict__ q,
                                               const unsigned short* __restrict__ k,
                                               const unsigned short* __restrict__ vt,
                                               unsigned short* __restrict__ obt) {
  // ush: K[16384] @0 (P overlays [0,8192)) | V[16384] @16384   (= 64 KiB)
  __shared__ __align__(16) unsigned short lds[32768];

  const int tid = threadIdx.x;
  const int wid = tid >> 6, lane = tid & 63;   // wid 0..7
  const int rowA = lane & 15, kg = lane >> 4;
  const int kgrp = kg * 8, rgrp = kg * 4;

  const int bid = blockIdx.x;          // 0..255
  const int xcd = bid & 7;             // round-robin XCD dispatch (perf-only)
  const int r0  = bid >> 3;            // 0..31
  const int bh  = xcd * 4 + (r0 & 3);  // 4 heads per XCD chunk
  const int p   = r0 >> 2;             // 0..7
  const int b = bh >> 4, h = bh & 15;

  const int jbs[2] = {15 - p, p};      // heavy segment first
  const int nt0 = jbs[0] + 1, nt1 = jbs[1] + 1;
  const int total = nt0 + nt1;         // = 17 for every block

  const unsigned short* qh  = q  + (size_t)bh * 2048 * 128;
  const unsigned short* kh  = k  + (size_t)bh * 2048 * 128;
  const unsigned short* vth = vt + (size_t)bh * 128 * 2048;

  const int srow4 = wid * 4 + (lane >> 4); // 0..31
  auto STAGE_K = [&](int kv0) {
#pragma unroll
    for (int c = 0; c < 4; ++c) {
      int row = c * 32 + srow4;
      int ch  = (lane & 15) ^ (row & 7);
      gload_lds16(kh + (size_t)(kv0 + row) * 128 + ch * 8,
                  (void*)&lds[(c * 32 + wid * 4) * 128]);
    }
  };
  auto STAGE_V = [&](int kv0) {
#pragma unroll
    for (int c = 0; c < 4; ++c) {
      int row = c * 32 + srow4;            // d-dim row
      int ch  = (lane & 15) ^ (row & 7);
      gload_lds16(vth + (size_t)row * 2048 + kv0 + ch * 8,
                  (void*)&lds[16384 + (c * 32 + wid * 4) * 128]);
    }
  };

  const f32x4 z4 = {0.f, 0.f, 0.f, 0.f};
  bf16x8 qf[4];
  f32x4 o[8];
  float mprev[4], lsum[4];
  int q0w = 0;

  int seg = 0, it = 0;
  STAGE_K(0);   // 4 oldest vmem ops/thread
  STAGE_V(0);   // 4 newest

  for (int u = 0; u < total; ++u) {
    const int nt = (seg == 0) ? nt0 : nt1;
    const int kv0 = it * 128;

    // ---- top gate: K(u) complete everywhere; V(u) may still fly ----
    asm volatile("s_waitcnt vmcnt(4)" ::: "memory");
    __builtin_amdgcn_s_barrier();
    __builtin_amdgcn_sched_barrier(0);

    if (it == 0) {   // segment init: Q fragments (16 rows/wave) + state reset
      q0w = jbs[seg] * 128 + wid * 16;
#pragma unroll
      for (int kq = 0; kq < 4; ++kq)
        qf[kq] = *(const bf16x8*)(qh + (size_t)(q0w + rowA) * 128 + kq * 32 + kgrp);
#pragma unroll
      for (int dn = 0; dn < 8; ++dn) o[dn] = z4;
#pragma unroll
      for (int r2 = 0; r2 < 4; ++r2) { mprev[r2] = -1e30f; lsum[r2] = 0.f; }
    }

    // ---- S = Q K^T over 128 kv (swizzled LDS) ----
    f32x4 s[8];
#pragma unroll
    for (int n = 0; n < 8; ++n) s[n] = z4;
    __builtin_amdgcn_s_setprio(1);
#pragma unroll
    for (int kq = 0; kq < 4; ++kq) {
#pragma unroll
      for (int n = 0; n < 8; ++n) {
        int row = n * 16 + rowA;
        int ch  = (kq * 4 + kg) ^ (row & 7);
        bf16x8 bkk = *(const bf16x8*)&lds[row * 128 + ch * 8];
        s[n] = __builtin_amdgcn_mfma_f32_16x16x32_bf16(qf[kq], bkk, s[n], 0, 0, 0);
      }
    }
    __builtin_amdgcn_s_setprio(0);

    // ---- mid gate: V(u) drained + K reads done -> P region free, V visible
    asm volatile("s_waitcnt vmcnt(0) lgkmcnt(0)" ::: "memory");
    __builtin_amdgcn_s_barrier();
    __builtin_amdgcn_sched_barrier(0);

    // ---- causal mask (only the diagonal tile) ----
    if (kv0 + 127 > q0w) {
#pragma unroll
      for (int n = 0; n < 8; ++n)
#pragma unroll
        for (int r2 = 0; r2 < 4; ++r2) {
          int qg = q0w + rgrp + r2;
          int kgl = kv0 + n * 16 + rowA;
          if (kgl > qg) s[n][r2] = -1e30f;
        }
    }

    // ---- online softmax (base-2), step-major trees, defer-max ----
    float tmax[4];
#pragma unroll
    for (int r2 = 0; r2 < 4; ++r2) {
      float t = s[0][r2];
#pragma unroll
      for (int n = 1; n < 8; ++n) t = fmaxf(t, s[n][r2]);
      tmax[r2] = t;
    }
#pragma unroll
    for (int stp = 1; stp <= 8; stp <<= 1)
#pragma unroll
      for (int r2 = 0; r2 < 4; ++r2)
        tmax[r2] = fmaxf(tmax[r2], __shfl_xor(tmax[r2], stp));

    bool ok = true;
#pragma unroll
    for (int r2 = 0; r2 < 4; ++r2) ok = ok && (tmax[r2] <= mprev[r2] + 8.0f);
    const bool skip = __all(ok ? 1 : 0);

    float mnew[4], psum[4];
#pragma unroll
    for (int r2 = 0; r2 < 4; ++r2) {
      mnew[r2] = skip ? mprev[r2] : fmaxf(mprev[r2], tmax[r2]);
      float ps = 0.f;
#pragma unroll
      for (int n = 0; n < 8; ++n) {
        float pv = exp2f(s[n][r2] - mnew[r2]);
        s[n][r2] = pv;
        ps += pv;
      }
      psum[r2] = ps;
    }
#pragma unroll
    for (int stp = 1; stp <= 8; stp <<= 1)
#pragma unroll
      for (int r2 = 0; r2 < 4; ++r2)
        psum[r2] += __shfl_xor(psum[r2], stp);

#pragma unroll
    for (int r2 = 0; r2 < 4; ++r2) {
      if (skip) {
        lsum[r2] += psum[r2];
      } else {
        float alpha = exp2f(mprev[r2] - mnew[r2]);
        lsum[r2] = lsum[r2] * alpha + psum[r2];
        mprev[r2] = mnew[r2];
#pragma unroll
        for (int dn = 0; dn < 8; ++dn) o[dn][r2] *= alpha;
      }
    }

    // ---- PV in two passes; P [16][64]/wave overlays Kbuf[0..8192 ush) ----
    unsigned short* Pw = &lds[wid * 1024];
    const unsigned short* Vb = &lds[16384];
#pragma unroll
    for (int pass = 0; pass < 2; ++pass) {
#pragma unroll
      for (int nl = 0; nl < 4; ++nl)
#pragma unroll
        for (int r2 = 0; r2 < 4; ++r2) {
          int row = rgrp + r2;
          int col = nl * 16 + rowA;
          Pw[row * 64 + (col ^ ((row & 7) << 3))] = f2bf(s[pass * 4 + nl][r2]);
        }
      // per-wave DS ordering: compiler inserts lgkmcnt waits before reads
      __builtin_amdgcn_s_setprio(1);
#pragma unroll
      for (int kkl = 0; kkl < 2; ++kkl) {
        const int kk = pass * 2 + kkl;
        bf16x8 pa;
        {
          int row = rowA;
          int col0 = kkl * 32 + kgrp;
          pa = *(const bf16x8*)&Pw[row * 64 + (col0 ^ ((row & 7) << 3))];
        }
#pragma unroll
        for (int dn = 0; dn < 8; ++dn) {
          int row = dn * 16 + rowA;
          int ch  = (kk * 4 + kg) ^ (row & 7);
          bf16x8 vb = *(const bf16x8*)&Vb[row * 128 + ch * 8];
          o[dn] = __builtin_amdgcn_mfma_f32_16x16x32_bf16(pa, vb, o[dn], 0, 0, 0);
        }
      }
      __builtin_amdgcn_s_setprio(0);
    }

    // ---- segment epilogue: normalize and write ----
    if (it == nt - 1) {
      float rinv[4];
#pragma unroll
      for (int r2 = 0; r2 < 4; ++r2) rinv[r2] = 1.0f / lsum[r2];
#pragma unroll
      for (int dn = 0; dn < 8; ++dn)
#pragma unroll
        for (int r2 = 0; r2 < 4; ++r2) {
          float v = o[dn][r2] * rinv[r2];
          int t = q0w + rgrp + r2;
          int col = h * 128 + dn * 16 + rowA;
          obt[((size_t)b * 2048 + t) * 2048 + col] = f2bf(v);
        }
    }

    __syncthreads(); // drains everything (vmcnt0+lgkmcnt0); buffers reusable

    // ---- stage next K and V (K first = oldest; gated at next top) ----
    if (u + 1 < total) {
      const int itn = (u + 1 >= nt0) ? (u + 1 - nt0) : (u + 1);
      STAGE_K(itn * 128);
      STAGE_V(itn * 128);
    }

    ++it;
    if (seg == 0 && it == nt0) { seg = 1; it = 0; }
  }
}

// ---- host launch -----------------------------------------------------------
extern "C" void kernel_launch(void* const* d_in, const int* in_sizes, int n_in,
                              void* d_out, int out_size, void* d_ws, size_t ws_size,
                              hipStream_t stream) {
  const float* x  = (const float*)d_in[0];
  const float* Wq = (const float*)d_in[2];
  const float* Wk = (const float*)d_in[3];
  const float* Wv = (const float*)d_in[4];
  const float* Wo = (const float*)d_in[5];
  float* out = (float*)d_out;

  char* ws = (char*)d_ws;
  unsigned short* xb  = (unsigned short*)(ws + 0);
  unsigned short* wqb = (unsigned short*)(ws + 16777216);
  unsigned short* wkb = (unsigned short*)(ws + 25165824);
  unsigned short* wvb = (unsigned short*)(ws + 33554432);
  unsigned short* wob = (unsigned short*)(ws + 41943040);
  unsigned short* qb  = (unsigned short*)(ws + 50331648);
  unsigned short* kb  = (unsigned short*)(ws + 67108864);
  unsigned short* vtb = (unsigned short*)(ws + 83886080);
  unsigned short* obt = (unsigned short*)(ws + 100663296);
  float* ct = (float*)(ws + 117440512);
  float* st = (float*)(ws + 117964800);

  k_cvt5<<<2048, 256, 0, stream>>>(x, Wq, Wk, Wv, Wo, xb, wqb, wkb, wvb, wob, ct, st);
  dim3 gq(48, 16); // merged QKV: 768 blocks = 3 even rounds; RoPE fused (vec)
  k_gemm256n128<1><<<gq, 512, 0, stream>>>(xb, wqb, wkb, wvb, nullptr, qb, kb, vtb, ct, st);
  k_flash<<<256, 512, 0, stream>>>(qb, kb, vtb, obt);
  dim3 go(16, 16); // Wo: 256 blocks = 1 full-chip round
  k_gemm256n128<0><<<go, 512, 0, stream>>>(obt, wob, nullptr, nullptr, out, nullptr, nullptr, nullptr, nullptr, nullptr);
}

// Round 28
// 251.330 us; speedup vs baseline: 1.0794x; 1.0345x over previous
//
#include <hip/hip_runtime.h>
#include <stdint.h>

#define AS1 __attribute__((address_space(1)))
#define AS3 __attribute__((address_space(3)))

using bf16x8 = __attribute__((ext_vector_type(8))) short;
using f32x4  = __attribute__((ext_vector_type(4))) float;

// ---- helpers -------------------------------------------------------------
__device__ __forceinline__ unsigned short f2bf(float f) {
  union { float f; unsigned u; } v; v.f = f;
  return (unsigned short)((v.u + 0x7FFFu + ((v.u >> 16) & 1u)) >> 16); // RNE
}
__device__ __forceinline__ float bf2f(unsigned short h) {
  union { unsigned u; float f; } v; v.u = ((unsigned)h) << 16;
  return v.f;
}
// async global->LDS, 16B per lane; lds dest must be wave-uniform base (HW adds lane*16)
__device__ __forceinline__ void gload_lds16(const void* g, void* l) {
  __builtin_amdgcn_global_load_lds((AS1 const void*)g, (AS3 void*)l, 16, 0, 0);
}

// ---- fused fp32->bf16 convert (x + 4 weights) + RoPE tables, one launch ----
__global__ void k_cvt5(const float* __restrict__ x,  const float* __restrict__ wq,
                       const float* __restrict__ wk, const float* __restrict__ wv,
                       const float* __restrict__ wo,
                       unsigned short* __restrict__ xb,  unsigned short* __restrict__ wqb,
                       unsigned short* __restrict__ wkb, unsigned short* __restrict__ wvb,
                       unsigned short* __restrict__ wob,
                       float* __restrict__ ct, float* __restrict__ st) {
  int idx = blockIdx.x * blockDim.x + threadIdx.x;
  int stride = gridDim.x * blockDim.x;
  for (int i = idx; i < 6422528; i += stride) {
    if (i >= 6291456) { // rope tables
      int j = i - 6291456;
      int t = j >> 6, fi = j & 63;
      float invf = exp2f(-(float)fi * (13.287712379549449f / 64.0f));
      float a = (float)t * invf;
      ct[j] = cosf(a);
      st[j] = sinf(a);
      continue;
    }
    const float* src; unsigned short* dst; int off;
    if (i < 2097152) { src = x; dst = xb; off = i; }
    else {
      int j = i - 2097152;
      int w = j >> 20;            // 1,048,576 float4 per weight
      off = j & 1048575;
      src = (w == 0) ? wq : (w == 1) ? wk : (w == 2) ? wv : wo;
      dst = (w == 0) ? wqb : (w == 1) ? wkb : (w == 2) ? wvb : wob;
    }
    float4 f = ((const float4*)src)[off];
    ushort4 o;
    o.x = f2bf(f.x); o.y = f2bf(f.y); o.z = f2bf(f.z); o.w = f2bf(f.w);
    ((ushort4*)dst)[off] = o;
  }
}

// ---- 256x128 GEMM, TRIPLE-buffered counted-vmcnt pipeline + fused RoPE -----
// r27's kernel with a 3rd A/B buffer (144KB LDS, still 1 block/CU): tile t+2's
// staging issues at the TOP of tile t's compute (its buffer held t-1, consumed
// and barrier-synced at end of t-1), so loads fly ~2 full compute phases before
// their vmcnt(6) gate (was ~1). Gate discipline unchanged: t+1 = 6 oldest
// retired, t+2 = 6 newest in flight; tail t=30 drains with vmcnt(0).
// MODE 0: f32 out [M,2048] (Wo, grid 16x16).  MODE 1: QKV (grid 48x16) with
// vectorized fused-RoPE epilogue (r27).
template <int MODE>
__global__ __launch_bounds__(512, 2) void k_gemm256n128(
    const unsigned short* __restrict__ Ag,
    const unsigned short* __restrict__ B0,
    const unsigned short* __restrict__ B1,
    const unsigned short* __restrict__ B2,
    float* __restrict__ outF,
    unsigned short* __restrict__ outQ,
    unsigned short* __restrict__ outK,
    unsigned short* __restrict__ outVT,
    const float* __restrict__ ctg,
    const float* __restrict__ stg) {
  // ush: A tbuf [3][16384] @0 (96KB) | B tbuf [3][4096..] @49152 (48KB) = 144KB
  __shared__ __align__(16) unsigned short lds[73728];

  const int tid = threadIdx.x;
  const int wid = tid >> 6, lane = tid & 63;
  const int wm = wid >> 1, wn = wid & 1;      // 4M x 2N wave grid
  const int rowA = lane & 15, kg = lane >> 4;
  const int rgrp = kg * 4;
  const int swz = rowA & 7;

  const int m0 = blockIdx.y * 256;
  const int n0g = blockIdx.x * 128;
  int w, n0;
  const unsigned short* Bg;
  if (MODE == 0) { w = 0; n0 = n0g; Bg = B0; }
  else { w = n0g >> 11; n0 = n0g & 2047; Bg = (w == 0) ? B0 : (w == 1) ? B1 : B2; }

  const int aBase = wm * 4096 + rowA * 64;
  const int bBase = wn * 4096 + rowA * 64;
  const int ch0 = (kg ^ swz) * 8;
  const int ch1 = ((4 + kg) ^ swz) * 8;

  const int grow = wid * 8 + (lane >> 3);
  const int gch  = ((lane & 7) ^ ((lane >> 3) & 7)) * 8;
  const int sdst = wid * 512;

  auto SA = [&](int dst, int t1, int c4) {
    gload_lds16(Ag + (size_t)(m0 + c4 * 64 + grow) * 2048 + t1 * 64 + gch,
                (void*)&lds[dst * 16384 + c4 * 4096 + sdst]);
  };
  auto SB = [&](int dst, int t1, int c2) {
    gload_lds16(Bg + (size_t)(n0 + c2 * 64 + grow) * 2048 + t1 * 64 + gch,
                (void*)&lds[49152 + dst * 8192 + c2 * 4096 + sdst]);
  };
  auto STAGE = [&](int dst, int t1) { // 6 gloads: the per-tile unit
    SA(dst, t1, 0); SA(dst, t1, 1); SA(dst, t1, 2); SA(dst, t1, 3);
    SB(dst, t1, 0); SB(dst, t1, 1);
  };

  f32x4 acc[4][4];
  const f32x4 z4 = {0.f, 0.f, 0.f, 0.f};
#pragma unroll
  for (int i = 0; i < 4; ++i)
#pragma unroll
    for (int j = 0; j < 4; ++j) acc[i][j] = z4;

  // prologue: stage t0 -> buf0 and t1 -> buf1; gate t0 (t1's 6 stay in flight)
  STAGE(0, 0);
  STAGE(1, 1);
  asm volatile("s_waitcnt vmcnt(6)" ::: "memory");
  __builtin_amdgcn_s_barrier();
  __builtin_amdgcn_sched_barrier(0);

  int cbuf = 0; // buffer holding tile t
  for (int t = 0; t < 32; ++t) {
    // ---- top: stage t+2 into the freed buffer (held t-1, synced) ----
    if (t + 2 < 32) {
      int nb = cbuf + 2; if (nb >= 3) nb -= 3;
      STAGE(nb, t + 2);
    }

    const int cA = cbuf * 16384, cB = 49152 + cbuf * 8192;
    bf16x8 af[4], bk[4];

    // ---- compute K-tile t from buf cbuf (both kk halves, 32 MFMA) ----
    __builtin_amdgcn_s_setprio(1);
#pragma unroll
    for (int i = 0; i < 4; ++i) af[i] = *(const bf16x8*)&lds[cA + aBase + i * 1024 + ch0];
#pragma unroll
    for (int j = 0; j < 4; ++j) bk[j] = *(const bf16x8*)&lds[cB + bBase + j * 1024 + ch0];
#pragma unroll
    for (int i = 0; i < 4; ++i)
#pragma unroll
      for (int j = 0; j < 4; ++j)
        acc[i][j] = __builtin_amdgcn_mfma_f32_16x16x32_bf16(af[i], bk[j], acc[i][j], 0, 0, 0);
#pragma unroll
    for (int i = 0; i < 4; ++i) af[i] = *(const bf16x8*)&lds[cA + aBase + i * 1024 + ch1];
#pragma unroll
    for (int j = 0; j < 4; ++j) bk[j] = *(const bf16x8*)&lds[cB + bBase + j * 1024 + ch1];
#pragma unroll
    for (int i = 0; i < 4; ++i)
#pragma unroll
      for (int j = 0; j < 4; ++j)
        acc[i][j] = __builtin_amdgcn_mfma_f32_16x16x32_bf16(af[i], bk[j], acc[i][j], 0, 0, 0);
    __builtin_amdgcn_s_setprio(0);

    if (t < 31) {
      // all waves done reading buf cbuf (it is re-staged at top of t+1)
      asm volatile("s_waitcnt lgkmcnt(0)" ::: "memory");
      __builtin_amdgcn_s_barrier();
      __builtin_amdgcn_sched_barrier(0);
      if (t + 2 < 32) {
        asm volatile("s_waitcnt vmcnt(6)" ::: "memory");  // t+1 retired; t+2 flying
      } else {
        asm volatile("s_waitcnt vmcnt(0)" ::: "memory");  // tail: drain t+1
      }
      __builtin_amdgcn_s_barrier();                       // publish t+1
      __builtin_amdgcn_sched_barrier(0);
    }

    cbuf = (cbuf + 1 == 3) ? 0 : cbuf + 1;
  }

  // ---- epilogue ----
  if (MODE == 1 && w < 2) {
    // fused RoPE: stage acc as bf16 [256][128] in LDS, pair (d, d+64)
    __syncthreads(); // all waves past their final tile-buffer reads
    unsigned short* Eb = lds;
#pragma unroll
    for (int i = 0; i < 4; ++i)
#pragma unroll
      for (int j = 0; j < 4; ++j)
#pragma unroll
        for (int r = 0; r < 4; ++r) {
          int ml = wm * 64 + i * 16 + rgrp + r;
          int dl = wn * 64 + j * 16 + rowA;
          Eb[ml * 128 + dl] = f2bf(acc[i][j][r]);
        }
    __syncthreads();
    unsigned short* C = w ? outK : outQ;
    const int h = n0 >> 7;            // BN=128: exactly one head per block
    const int d0 = (tid & 15) * 4;    // 4 consecutive d per thread
    const int g  = tid >> 4;          // 32 groups x 8 rows
    const float SC2 = 0.12751659974141322f; // (1/sqrt(128))*log2(e), Q only
#pragma unroll
    for (int mi = 0; mi < 8; ++mi) {
      int m = g * 8 + mi;
      int gm = m0 + m;
      int t = gm & 2047, b = gm >> 11;
      ushort4 a1 = *(const ushort4*)&Eb[m * 128 + d0];
      ushort4 a2 = *(const ushort4*)&Eb[m * 128 + d0 + 64];
      float4 cc = *(const float4*)&ctg[t * 64 + d0];
      float4 ss = *(const float4*)&stg[t * 64 + d0];
      float x1[4] = {bf2f(a1.x), bf2f(a1.y), bf2f(a1.z), bf2f(a1.w)};
      float x2[4] = {bf2f(a2.x), bf2f(a2.y), bf2f(a2.z), bf2f(a2.w)};
      float cv[4] = {cc.x, cc.y, cc.z, cc.w};
      float sv[4] = {ss.x, ss.y, ss.z, ss.w};
      ushort4 o1, o2;
      unsigned short* po1 = (unsigned short*)&o1;
      unsigned short* po2 = (unsigned short*)&o2;
#pragma unroll
      for (int e = 0; e < 4; ++e) {
        float y1 = x1[e] * cv[e] - x2[e] * sv[e];
        float y2 = x2[e] * cv[e] + x1[e] * sv[e];
        if (w == 0) { y1 *= SC2; y2 *= SC2; }
        po1[e] = f2bf(y1);
        po2[e] = f2bf(y2);
      }
      size_t base = ((size_t)(b * 16 + h) * 2048 + t) * 128;
      *(ushort4*)&C[base + d0]      = o1;
      *(ushort4*)&C[base + d0 + 64] = o2;
    }
  } else {
#pragma unroll
    for (int i = 0; i < 4; ++i) {
#pragma unroll
      for (int j = 0; j < 4; ++j) {
        const int gm0 = m0 + wm * 64 + i * 16 + rgrp;
        const int gn  = n0 + wn * 64 + j * 16 + rowA;
        if (MODE == 0) {
#pragma unroll
          for (int r = 0; r < 4; ++r)
            outF[(size_t)(gm0 + r) * 2048 + gn] = acc[i][j][r];
        } else { // w == 2: transposed V
          int h = gn >> 7, dd = gn & 127;
          int b = gm0 >> 11, tt = gm0 & 2047;
          ushort4 pk;
          pk.x = f2bf(acc[i][j][0]); pk.y = f2bf(acc[i][j][1]);
          pk.z = f2bf(acc[i][j][2]); pk.w = f2bf(acc[i][j][3]);
          *(ushort4*)&outVT[(((size_t)(b * 16 + h)) * 128 + dd) * 2048 + tt] = pk;
        }
      }
    }
  }
}

// ---- flash attention fwd: EXACT r21 kernel (8 waves x 16 q-rows, ~100us) ---
__global__ __launch_bounds__(512) void k_flash(const unsigned short* __restrict__ q,
                                               const unsigned short* __restrict__ k,
                                               const unsigned short* __restrict__ vt,
                                               unsigned short* __restrict__ obt) {
  // ush: K[16384] @0 (P overlays [0,8192)) | V[16384] @16384   (= 64 KiB)
  __shared__ __align__(16) unsigned short lds[32768];

  const int tid = threadIdx.x;
  const int wid = tid >> 6, lane = tid & 63;   // wid 0..7
  const int rowA = lane & 15, kg = lane >> 4;
  const int kgrp = kg * 8, rgrp = kg * 4;

  const int bid = blockIdx.x;          // 0..255
  const int xcd = bid & 7;             // round-robin XCD dispatch (perf-only)
  const int r0  = bid >> 3;            // 0..31
  const int bh  = xcd * 4 + (r0 & 3);  // 4 heads per XCD chunk
  const int p   = r0 >> 2;             // 0..7
  const int b = bh >> 4, h = bh & 15;

  const int jbs[2] = {15 - p, p};      // heavy segment first
  const int nt0 = jbs[0] + 1, nt1 = jbs[1] + 1;
  const int total = nt0 + nt1;         // = 17 for every block

  const unsigned short* qh  = q  + (size_t)bh * 2048 * 128;
  const unsigned short* kh  = k  + (size_t)bh * 2048 * 128;
  const unsigned short* vth = vt + (size_t)bh * 128 * 2048;

  const int srow4 = wid * 4 + (lane >> 4); // 0..31
  auto STAGE_K = [&](int kv0) {
#pragma unroll
    for (int c = 0; c < 4; ++c) {
      int row = c * 32 + srow4;
      int ch  = (lane & 15) ^ (row & 7);
      gload_lds16(kh + (size_t)(kv0 + row) * 128 + ch * 8,
                  (void*)&lds[(c * 32 + wid * 4) * 128]);
    }
  };
  auto STAGE_V = [&](int kv0) {
#pragma unroll
    for (int c = 0; c < 4; ++c) {
      int row = c * 32 + srow4;            // d-dim row
      int ch  = (lane & 15) ^ (row & 7);
      gload_lds16(vth + (size_t)row * 2048 + kv0 + ch * 8,
                  (void*)&lds[16384 + (c * 32 + wid * 4) * 128]);
    }
  };

  const f32x4 z4 = {0.f, 0.f, 0.f, 0.f};
  bf16x8 qf[4];
  f32x4 o[8];
  float mprev[4], lsum[4];
  int q0w = 0;

  int seg = 0, it = 0;
  STAGE_K(0);   // 4 oldest vmem ops/thread
  STAGE_V(0);   // 4 newest

  for (int u = 0; u < total; ++u) {
    const int nt = (seg == 0) ? nt0 : nt1;
    const int kv0 = it * 128;

    // ---- top gate: K(u) complete everywhere; V(u) may still fly ----
    asm volatile("s_waitcnt vmcnt(4)" ::: "memory");
    __builtin_amdgcn_s_barrier();
    __builtin_amdgcn_sched_barrier(0);

    if (it == 0) {   // segment init: Q fragments (16 rows/wave) + state reset
      q0w = jbs[seg] * 128 + wid * 16;
#pragma unroll
      for (int kq = 0; kq < 4; ++kq)
        qf[kq] = *(const bf16x8*)(qh + (size_t)(q0w + rowA) * 128 + kq * 32 + kgrp);
#pragma unroll
      for (int dn = 0; dn < 8; ++dn) o[dn] = z4;
#pragma unroll
      for (int r2 = 0; r2 < 4; ++r2) { mprev[r2] = -1e30f; lsum[r2] = 0.f; }
    }

    // ---- S = Q K^T over 128 kv (swizzled LDS) ----
    f32x4 s[8];
#pragma unroll
    for (int n = 0; n < 8; ++n) s[n] = z4;
    __builtin_amdgcn_s_setprio(1);
#pragma unroll
    for (int kq = 0; kq < 4; ++kq) {
#pragma unroll
      for (int n = 0; n < 8; ++n) {
        int row = n * 16 + rowA;
        int ch  = (kq * 4 + kg) ^ (row & 7);
        bf16x8 bkk = *(const bf16x8*)&lds[row * 128 + ch * 8];
        s[n] = __builtin_amdgcn_mfma_f32_16x16x32_bf16(qf[kq], bkk, s[n], 0, 0, 0);
      }
    }
    __builtin_amdgcn_s_setprio(0);

    // ---- mid gate: V(u) drained + K reads done -> P region free, V visible
    asm volatile("s_waitcnt vmcnt(0) lgkmcnt(0)" ::: "memory");
    __builtin_amdgcn_s_barrier();
    __builtin_amdgcn_sched_barrier(0);

    // ---- causal mask (only the diagonal tile) ----
    if (kv0 + 127 > q0w) {
#pragma unroll
      for (int n = 0; n < 8; ++n)
#pragma unroll
        for (int r2 = 0; r2 < 4; ++r2) {
          int qg = q0w + rgrp + r2;
          int kgl = kv0 + n * 16 + rowA;
          if (kgl > qg) s[n][r2] = -1e30f;
        }
    }

    // ---- online softmax (base-2), step-major trees, defer-max ----
    float tmax[4];
#pragma unroll
    for (int r2 = 0; r2 < 4; ++r2) {
      float t = s[0][r2];
#pragma unroll
      for (int n = 1; n < 8; ++n) t = fmaxf(t, s[n][r2]);
      tmax[r2] = t;
    }
#pragma unroll
    for (int stp = 1; stp <= 8; stp <<= 1)
#pragma unroll
      for (int r2 = 0; r2 < 4; ++r2)
        tmax[r2] = fmaxf(tmax[r2], __shfl_xor(tmax[r2], stp));

    bool ok = true;
#pragma unroll
    for (int r2 = 0; r2 < 4; ++r2) ok = ok && (tmax[r2] <= mprev[r2] + 8.0f);
    const bool skip = __all(ok ? 1 : 0);

    float mnew[4], psum[4];
#pragma unroll
    for (int r2 = 0; r2 < 4; ++r2) {
      mnew[r2] = skip ? mprev[r2] : fmaxf(mprev[r2], tmax[r2]);
      float ps = 0.f;
#pragma unroll
      for (int n = 0; n < 8; ++n) {
        float pv = exp2f(s[n][r2] - mnew[r2]);
        s[n][r2] = pv;
        ps += pv;
      }
      psum[r2] = ps;
    }
#pragma unroll
    for (int stp = 1; stp <= 8; stp <<= 1)
#pragma unroll
      for (int r2 = 0; r2 < 4; ++r2)
        psum[r2] += __shfl_xor(psum[r2], stp);

#pragma unroll
    for (int r2 = 0; r2 < 4; ++r2) {
      if (skip) {
        lsum[r2] += psum[r2];
      } else {
        float alpha = exp2f(mprev[r2] - mnew[r2]);
        lsum[r2] = lsum[r2] * alpha + psum[r2];
        mprev[r2] = mnew[r2];
#pragma unroll
        for (int dn = 0; dn < 8; ++dn) o[dn][r2] *= alpha;
      }
    }

    // ---- PV in two passes; P [16][64]/wave overlays Kbuf[0..8192 ush) ----
    unsigned short* Pw = &lds[wid * 1024];
    const unsigned short* Vb = &lds[16384];
#pragma unroll
    for (int pass = 0; pass < 2; ++pass) {
#pragma unroll
      for (int nl = 0; nl < 4; ++nl)
#pragma unroll
        for (int r2 = 0; r2 < 4; ++r2) {
          int row = rgrp + r2;
          int col = nl * 16 + rowA;
          Pw[row * 64 + (col ^ ((row & 7) << 3))] = f2bf(s[pass * 4 + nl][r2]);
        }
      // per-wave DS ordering: compiler inserts lgkmcnt waits before reads
      __builtin_amdgcn_s_setprio(1);
#pragma unroll
      for (int kkl = 0; kkl < 2; ++kkl) {
        const int kk = pass * 2 + kkl;
        bf16x8 pa;
        {
          int row = rowA;
          int col0 = kkl * 32 + kgrp;
          pa = *(const bf16x8*)&Pw[row * 64 + (col0 ^ ((row & 7) << 3))];
        }
#pragma unroll
        for (int dn = 0; dn < 8; ++dn) {
          int row = dn * 16 + rowA;
          int ch  = (kk * 4 + kg) ^ (row & 7);
          bf16x8 vb = *(const bf16x8*)&Vb[row * 128 + ch * 8];
          o[dn] = __builtin_amdgcn_mfma_f32_16x16x32_bf16(pa, vb, o[dn], 0, 0, 0);
        }
      }
      __builtin_amdgcn_s_setprio(0);
    }

    // ---- segment epilogue: normalize and write ----
    if (it == nt - 1) {
      float rinv[4];
#pragma unroll
      for (int r2 = 0; r2 < 4; ++r2) rinv[r2] = 1.0f / lsum[r2];
#pragma unroll
      for (int dn = 0; dn < 8; ++dn)
#pragma unroll
        for (int r2 = 0; r2 < 4; ++r2) {
          float v = o[dn][r2] * rinv[r2];
          int t = q0w + rgrp + r2;
          int col = h * 128 + dn * 16 + rowA;
          obt[((size_t)b * 2048 + t) * 2048 + col] = f2bf(v);
        }
    }

    __syncthreads(); // drains everything (vmcnt0+lgkmcnt0); buffers reusable

    // ---- stage next K and V (K first = oldest; gated at next top) ----
    if (u + 1 < total) {
      const int itn = (u + 1 >= nt0) ? (u + 1 - nt0) : (u + 1);
      STAGE_K(itn * 128);
      STAGE_V(itn * 128);
    }

    ++it;
    if (seg == 0 && it == nt0) { seg = 1; it = 0; }
  }
}

// ---- host launch -----------------------------------------------------------
extern "C" void kernel_launch(void* const* d_in, const int* in_sizes, int n_in,
                              void* d_out, int out_size, void* d_ws, size_t ws_size,
                              hipStream_t stream) {
  const float* x  = (const float*)d_in[0];
  const float* Wq = (const float*)d_in[2];
  const float* Wk = (const float*)d_in[3];
  const float* Wv = (const float*)d_in[4];
  const float* Wo = (const float*)d_in[5];
  float* out = (float*)d_out;

  char* ws = (char*)d_ws;
  unsigned short* xb  = (unsigned short*)(ws + 0);
  unsigned short* wqb = (unsigned short*)(ws + 16777216);
  unsigned short* wkb = (unsigned short*)(ws + 25165824);
  unsigned short* wvb = (unsigned short*)(ws + 33554432);
  unsigned short* wob = (unsigned short*)(ws + 41943040);
  unsigned short* qb  = (unsigned short*)(ws + 50331648);
  unsigned short* kb  = (unsigned short*)(ws + 67108864);
  unsigned short* vtb = (unsigned short*)(ws + 83886080);
  unsigned short* obt = (unsigned short*)(ws + 100663296);
  float* ct = (float*)(ws + 117440512);
  float* st = (float*)(ws + 117964800);

  k_cvt5<<<2048, 256, 0, stream>>>(x, Wq, Wk, Wv, Wo, xb, wqb, wkb, wvb, wob, ct, st);
  dim3 gq(48, 16); // merged QKV: 768 blocks = 3 even rounds; RoPE fused (vec)
  k_gemm256n128<1><<<gq, 512, 0, stream>>>(xb, wqb, wkb, wvb, nullptr, qb, kb, vtb, ct, st);
  k_flash<<<256, 512, 0, stream>>>(qb, kb, vtb, obt);
  dim3 go(16, 16); // Wo: 256 blocks = 1 full-chip round
  k_gemm256n128<0><<<go, 512, 0, stream>>>(obt, wob, nullptr, nullptr, out, nullptr, nullptr, nullptr, nullptr, nullptr);
}

// Round 29
// 247.814 us; speedup vs baseline: 1.0947x; 1.0142x over previous
//
#include <hip/hip_runtime.h>
#include <stdint.h>

#define AS1 __attribute__((address_space(1)))
#define AS3 __attribute__((address_space(3)))

using bf16x8 = __attribute__((ext_vector_type(8))) short;
using f32x4  = __attribute__((ext_vector_type(4))) float;

// ---- helpers -------------------------------------------------------------
__device__ __forceinline__ unsigned short f2bf(float f) {
  union { float f; unsigned u; } v; v.f = f;
  return (unsigned short)((v.u + 0x7FFFu + ((v.u >> 16) & 1u)) >> 16); // RNE
}
__device__ __forceinline__ float bf2f(unsigned short h) {
  union { unsigned u; float f; } v; v.u = ((unsigned)h) << 16;
  return v.f;
}
// async global->LDS, 16B per lane; lds dest must be wave-uniform base (HW adds lane*16)
__device__ __forceinline__ void gload_lds16(const void* g, void* l) {
  __builtin_amdgcn_global_load_lds((AS1 const void*)g, (AS3 void*)l, 16, 0, 0);
}

// ---- fused fp32->bf16 convert (x + 4 weights) + RoPE tables, one launch ----
__global__ void k_cvt5(const float* __restrict__ x,  const float* __restrict__ wq,
                       const float* __restrict__ wk, const float* __restrict__ wv,
                       const float* __restrict__ wo,
                       unsigned short* __restrict__ xb,  unsigned short* __restrict__ wqb,
                       unsigned short* __restrict__ wkb, unsigned short* __restrict__ wvb,
                       unsigned short* __restrict__ wob,
                       float* __restrict__ ct, float* __restrict__ st) {
  int idx = blockIdx.x * blockDim.x + threadIdx.x;
  int stride = gridDim.x * blockDim.x;
  for (int i = idx; i < 6422528; i += stride) {
    if (i >= 6291456) { // rope tables
      int j = i - 6291456;
      int t = j >> 6, fi = j & 63;
      float invf = exp2f(-(float)fi * (13.287712379549449f / 64.0f));
      float a = (float)t * invf;
      ct[j] = cosf(a);
      st[j] = sinf(a);
      continue;
    }
    const float* src; unsigned short* dst; int off;
    if (i < 2097152) { src = x; dst = xb; off = i; }
    else {
      int j = i - 2097152;
      int w = j >> 20;            // 1,048,576 float4 per weight
      off = j & 1048575;
      src = (w == 0) ? wq : (w == 1) ? wk : (w == 2) ? wv : wo;
      dst = (w == 0) ? wqb : (w == 1) ? wkb : (w == 2) ? wvb : wob;
    }
    float4 f = ((const float4*)src)[off];
    ushort4 o;
    o.x = f2bf(f.x); o.y = f2bf(f.y); o.z = f2bf(f.z); o.w = f2bf(f.w);
    ((ushort4*)dst)[off] = o;
  }
}

// ---- 256x128 GEMM, TRIPLE-buffered counted-vmcnt pipeline + fused RoPE -----
// EXACT r28 kernel (verified: QKV ~119us, Wo ~13us, total 251.3).
template <int MODE>
__global__ __launch_bounds__(512, 2) void k_gemm256n128(
    const unsigned short* __restrict__ Ag,
    const unsigned short* __restrict__ B0,
    const unsigned short* __restrict__ B1,
    const unsigned short* __restrict__ B2,
    float* __restrict__ outF,
    unsigned short* __restrict__ outQ,
    unsigned short* __restrict__ outK,
    unsigned short* __restrict__ outVT,
    const float* __restrict__ ctg,
    const float* __restrict__ stg) {
  // ush: A tbuf [3][16384] @0 (96KB) | B tbuf [3][4096..] @49152 (48KB) = 144KB
  __shared__ __align__(16) unsigned short lds[73728];

  const int tid = threadIdx.x;
  const int wid = tid >> 6, lane = tid & 63;
  const int wm = wid >> 1, wn = wid & 1;      // 4M x 2N wave grid
  const int rowA = lane & 15, kg = lane >> 4;
  const int rgrp = kg * 4;
  const int swz = rowA & 7;

  const int m0 = blockIdx.y * 256;
  const int n0g = blockIdx.x * 128;
  int w, n0;
  const unsigned short* Bg;
  if (MODE == 0) { w = 0; n0 = n0g; Bg = B0; }
  else { w = n0g >> 11; n0 = n0g & 2047; Bg = (w == 0) ? B0 : (w == 1) ? B1 : B2; }

  const int aBase = wm * 4096 + rowA * 64;
  const int bBase = wn * 4096 + rowA * 64;
  const int ch0 = (kg ^ swz) * 8;
  const int ch1 = ((4 + kg) ^ swz) * 8;

  const int grow = wid * 8 + (lane >> 3);
  const int gch  = ((lane & 7) ^ ((lane >> 3) & 7)) * 8;
  const int sdst = wid * 512;

  auto SA = [&](int dst, int t1, int c4) {
    gload_lds16(Ag + (size_t)(m0 + c4 * 64 + grow) * 2048 + t1 * 64 + gch,
                (void*)&lds[dst * 16384 + c4 * 4096 + sdst]);
  };
  auto SB = [&](int dst, int t1, int c2) {
    gload_lds16(Bg + (size_t)(n0 + c2 * 64 + grow) * 2048 + t1 * 64 + gch,
                (void*)&lds[49152 + dst * 8192 + c2 * 4096 + sdst]);
  };
  auto STAGE = [&](int dst, int t1) { // 6 gloads: the per-tile unit
    SA(dst, t1, 0); SA(dst, t1, 1); SA(dst, t1, 2); SA(dst, t1, 3);
    SB(dst, t1, 0); SB(dst, t1, 1);
  };

  f32x4 acc[4][4];
  const f32x4 z4 = {0.f, 0.f, 0.f, 0.f};
#pragma unroll
  for (int i = 0; i < 4; ++i)
#pragma unroll
    for (int j = 0; j < 4; ++j) acc[i][j] = z4;

  // prologue: stage t0 -> buf0 and t1 -> buf1; gate t0 (t1's 6 stay in flight)
  STAGE(0, 0);
  STAGE(1, 1);
  asm volatile("s_waitcnt vmcnt(6)" ::: "memory");
  __builtin_amdgcn_s_barrier();
  __builtin_amdgcn_sched_barrier(0);

  int cbuf = 0; // buffer holding tile t
  for (int t = 0; t < 32; ++t) {
    // ---- top: stage t+2 into the freed buffer (held t-1, synced) ----
    if (t + 2 < 32) {
      int nb = cbuf + 2; if (nb >= 3) nb -= 3;
      STAGE(nb, t + 2);
    }

    const int cA = cbuf * 16384, cB = 49152 + cbuf * 8192;
    bf16x8 af[4], bk[4];

    // ---- compute K-tile t from buf cbuf (both kk halves, 32 MFMA) ----
    __builtin_amdgcn_s_setprio(1);
#pragma unroll
    for (int i = 0; i < 4; ++i) af[i] = *(const bf16x8*)&lds[cA + aBase + i * 1024 + ch0];
#pragma unroll
    for (int j = 0; j < 4; ++j) bk[j] = *(const bf16x8*)&lds[cB + bBase + j * 1024 + ch0];
#pragma unroll
    for (int i = 0; i < 4; ++i)
#pragma unroll
      for (int j = 0; j < 4; ++j)
        acc[i][j] = __builtin_amdgcn_mfma_f32_16x16x32_bf16(af[i], bk[j], acc[i][j], 0, 0, 0);
#pragma unroll
    for (int i = 0; i < 4; ++i) af[i] = *(const bf16x8*)&lds[cA + aBase + i * 1024 + ch1];
#pragma unroll
    for (int j = 0; j < 4; ++j) bk[j] = *(const bf16x8*)&lds[cB + bBase + j * 1024 + ch1];
#pragma unroll
    for (int i = 0; i < 4; ++i)
#pragma unroll
      for (int j = 0; j < 4; ++j)
        acc[i][j] = __builtin_amdgcn_mfma_f32_16x16x32_bf16(af[i], bk[j], acc[i][j], 0, 0, 0);
    __builtin_amdgcn_s_setprio(0);

    if (t < 31) {
      // all waves done reading buf cbuf (it is re-staged at top of t+1)
      asm volatile("s_waitcnt lgkmcnt(0)" ::: "memory");
      __builtin_amdgcn_s_barrier();
      __builtin_amdgcn_sched_barrier(0);
      if (t + 2 < 32) {
        asm volatile("s_waitcnt vmcnt(6)" ::: "memory");  // t+1 retired; t+2 flying
      } else {
        asm volatile("s_waitcnt vmcnt(0)" ::: "memory");  // tail: drain t+1
      }
      __builtin_amdgcn_s_barrier();                       // publish t+1
      __builtin_amdgcn_sched_barrier(0);
    }

    cbuf = (cbuf + 1 == 3) ? 0 : cbuf + 1;
  }

  // ---- epilogue ----
  if (MODE == 1 && w < 2) {
    // fused RoPE: stage acc as bf16 [256][128] in LDS, pair (d, d+64)
    __syncthreads(); // all waves past their final tile-buffer reads
    unsigned short* Eb = lds;
#pragma unroll
    for (int i = 0; i < 4; ++i)
#pragma unroll
      for (int j = 0; j < 4; ++j)
#pragma unroll
        for (int r = 0; r < 4; ++r) {
          int ml = wm * 64 + i * 16 + rgrp + r;
          int dl = wn * 64 + j * 16 + rowA;
          Eb[ml * 128 + dl] = f2bf(acc[i][j][r]);
        }
    __syncthreads();
    unsigned short* C = w ? outK : outQ;
    const int h = n0 >> 7;            // BN=128: exactly one head per block
    const int d0 = (tid & 15) * 4;    // 4 consecutive d per thread
    const int g  = tid >> 4;          // 32 groups x 8 rows
    const float SC2 = 0.12751659974141322f; // (1/sqrt(128))*log2(e), Q only
#pragma unroll
    for (int mi = 0; mi < 8; ++mi) {
      int m = g * 8 + mi;
      int gm = m0 + m;
      int t = gm & 2047, b = gm >> 11;
      ushort4 a1 = *(const ushort4*)&Eb[m * 128 + d0];
      ushort4 a2 = *(const ushort4*)&Eb[m * 128 + d0 + 64];
      float4 cc = *(const float4*)&ctg[t * 64 + d0];
      float4 ss = *(const float4*)&stg[t * 64 + d0];
      float x1[4] = {bf2f(a1.x), bf2f(a1.y), bf2f(a1.z), bf2f(a1.w)};
      float x2[4] = {bf2f(a2.x), bf2f(a2.y), bf2f(a2.z), bf2f(a2.w)};
      float cv[4] = {cc.x, cc.y, cc.z, cc.w};
      float sv[4] = {ss.x, ss.y, ss.z, ss.w};
      ushort4 o1, o2;
      unsigned short* po1 = (unsigned short*)&o1;
      unsigned short* po2 = (unsigned short*)&o2;
#pragma unroll
      for (int e = 0; e < 4; ++e) {
        float y1 = x1[e] * cv[e] - x2[e] * sv[e];
        float y2 = x2[e] * cv[e] + x1[e] * sv[e];
        if (w == 0) { y1 *= SC2; y2 *= SC2; }
        po1[e] = f2bf(y1);
        po2[e] = f2bf(y2);
      }
      size_t base = ((size_t)(b * 16 + h) * 2048 + t) * 128;
      *(ushort4*)&C[base + d0]      = o1;
      *(ushort4*)&C[base + d0 + 64] = o2;
    }
  } else {
#pragma unroll
    for (int i = 0; i < 4; ++i) {
#pragma unroll
      for (int j = 0; j < 4; ++j) {
        const int gm0 = m0 + wm * 64 + i * 16 + rgrp;
        const int gn  = n0 + wn * 64 + j * 16 + rowA;
        if (MODE == 0) {
#pragma unroll
          for (int r = 0; r < 4; ++r)
            outF[(size_t)(gm0 + r) * 2048 + gn] = acc[i][j][r];
        } else { // w == 2: transposed V
          int h = gn >> 7, dd = gn & 127;
          int b = gm0 >> 11, tt = gm0 & 2047;
          ushort4 pk;
          pk.x = f2bf(acc[i][j][0]); pk.y = f2bf(acc[i][j][1]);
          pk.z = f2bf(acc[i][j][2]); pk.w = f2bf(acc[i][j][3]);
          *(ushort4*)&outVT[(((size_t)(b * 16 + h)) * 128 + dd) * 2048 + tt] = pk;
        }
      }
    }
  }
}

// ---- flash attention fwd: 8 waves x 16 q-rows, K DOUBLE-buffered pipeline --
// r21/r28 flash + counted K pipeline (same T4 discipline that won on the GEMM):
// K dbuf [2][16384] + V [16384] + P own region (112KB, 1 block/CU). Issue
// order per iteration end: V(u+1) then K(u+2) (into buf u&1, whose reads were
// lgkm-barriered at mid-u). FIFO gates (steady state): top of u needs K(u),
// {V(u),K(u+1)} = 8 newer -> vmcnt(8); mid needs V(u), K(u+1) = 4 newer ->
// vmcnt(4)+lgkmcnt(0). Tails: vmcnt(4)/vmcnt(0). Q-frag loads and epilogue
// stores only make gates conservative (over-wait), never unsafe. Every load
// now flies a FULL iteration before its gate (was: K waited immediately).
__global__ __launch_bounds__(512) void k_flash(const unsigned short* __restrict__ q,
                                               const unsigned short* __restrict__ k,
                                               const unsigned short* __restrict__ vt,
                                               unsigned short* __restrict__ obt) {
  // ush: K dbuf [2][16384] @0 | V[16384] @32768 | P 8x1024 @49152  (= 112 KiB)
  __shared__ __align__(16) unsigned short lds[57344];

  const int tid = threadIdx.x;
  const int wid = tid >> 6, lane = tid & 63;   // wid 0..7
  const int rowA = lane & 15, kg = lane >> 4;
  const int kgrp = kg * 8, rgrp = kg * 4;

  const int bid = blockIdx.x;          // 0..255
  const int xcd = bid & 7;             // round-robin XCD dispatch (perf-only)
  const int r0  = bid >> 3;            // 0..31
  const int bh  = xcd * 4 + (r0 & 3);  // 4 heads per XCD chunk
  const int p   = r0 >> 2;             // 0..7
  const int b = bh >> 4, h = bh & 15;

  const int jbs[2] = {15 - p, p};      // heavy segment first
  const int nt0 = jbs[0] + 1, nt1 = jbs[1] + 1;
  const int total = nt0 + nt1;         // = 17 for every block

  const unsigned short* qh  = q  + (size_t)bh * 2048 * 128;
  const unsigned short* kh  = k  + (size_t)bh * 2048 * 128;
  const unsigned short* vth = vt + (size_t)bh * 128 * 2048;

  const int srow4 = wid * 4 + (lane >> 4); // 0..31
  auto STAGE_K = [&](int buf, int kv0) {
#pragma unroll
    for (int c = 0; c < 4; ++c) {
      int row = c * 32 + srow4;
      int ch  = (lane & 15) ^ (row & 7);
      gload_lds16(kh + (size_t)(kv0 + row) * 128 + ch * 8,
                  (void*)&lds[buf * 16384 + (c * 32 + wid * 4) * 128]);
    }
  };
  auto STAGE_V = [&](int kv0) {
#pragma unroll
    for (int c = 0; c < 4; ++c) {
      int row = c * 32 + srow4;            // d-dim row
      int ch  = (lane & 15) ^ (row & 7);
      gload_lds16(vth + (size_t)row * 2048 + kv0 + ch * 8,
                  (void*)&lds[32768 + (c * 32 + wid * 4) * 128]);
    }
  };

  const f32x4 z4 = {0.f, 0.f, 0.f, 0.f};
  bf16x8 qf[4];
  f32x4 o[8];
  float mprev[4], lsum[4];
  int q0w = 0;

  int seg = 0, it = 0;
  // prologue: K(0) -> buf0, V(0), K(1) -> buf1 (tile 1 always in seg0: nt0>=9).
  // Order matters for FIFO gates: V(0) must be OLDER than K(1).
  STAGE_K(0, 0);
  STAGE_V(0);
  STAGE_K(1, 128);

  for (int u = 0; u < total; ++u) {
    const int nt = (seg == 0) ? nt0 : nt1;
    const int kv0 = it * 128;

    // ---- top gate: K(u) complete; V(u)+K(u+1) (8) stay in flight ----
    if (u + 1 < total) { asm volatile("s_waitcnt vmcnt(8)" ::: "memory"); }
    else               { asm volatile("s_waitcnt vmcnt(4)" ::: "memory"); }
    __builtin_amdgcn_s_barrier();
    __builtin_amdgcn_sched_barrier(0);

    if (it == 0) {   // segment init: Q fragments (16 rows/wave) + state reset
      q0w = jbs[seg] * 128 + wid * 16;
#pragma unroll
      for (int kq = 0; kq < 4; ++kq)
        qf[kq] = *(const bf16x8*)(qh + (size_t)(q0w + rowA) * 128 + kq * 32 + kgrp);
#pragma unroll
      for (int dn = 0; dn < 8; ++dn) o[dn] = z4;
#pragma unroll
      for (int r2 = 0; r2 < 4; ++r2) { mprev[r2] = -1e30f; lsum[r2] = 0.f; }
    }

    // ---- S = Q K^T over 128 kv (swizzled LDS, K buffer u&1) ----
    const unsigned short* Kb = &lds[(u & 1) * 16384];
    f32x4 s[8];
#pragma unroll
    for (int n = 0; n < 8; ++n) s[n] = z4;
    __builtin_amdgcn_s_setprio(1);
#pragma unroll
    for (int kq = 0; kq < 4; ++kq) {
#pragma unroll
      for (int n = 0; n < 8; ++n) {
        int row = n * 16 + rowA;
        int ch  = (kq * 4 + kg) ^ (row & 7);
        bf16x8 bkk = *(const bf16x8*)&Kb[row * 128 + ch * 8];
        s[n] = __builtin_amdgcn_mfma_f32_16x16x32_bf16(qf[kq], bkk, s[n], 0, 0, 0);
      }
    }
    __builtin_amdgcn_s_setprio(0);

    // ---- mid gate: V(u) done (K(u+1)'s 4 stay in flight) + K reads done ----
    if (u + 1 < total) { asm volatile("s_waitcnt vmcnt(4) lgkmcnt(0)" ::: "memory"); }
    else               { asm volatile("s_waitcnt vmcnt(0) lgkmcnt(0)" ::: "memory"); }
    __builtin_amdgcn_s_barrier();
    __builtin_amdgcn_sched_barrier(0);

    // ---- causal mask (only the diagonal tile) ----
    if (kv0 + 127 > q0w) {
#pragma unroll
      for (int n = 0; n < 8; ++n)
#pragma unroll
        for (int r2 = 0; r2 < 4; ++r2) {
          int qg = q0w + rgrp + r2;
          int kgl = kv0 + n * 16 + rowA;
          if (kgl > qg) s[n][r2] = -1e30f;
        }
    }

    // ---- online softmax (base-2), step-major trees, defer-max ----
    float tmax[4];
#pragma unroll
    for (int r2 = 0; r2 < 4; ++r2) {
      float t = s[0][r2];
#pragma unroll
      for (int n = 1; n < 8; ++n) t = fmaxf(t, s[n][r2]);
      tmax[r2] = t;
    }
#pragma unroll
    for (int stp = 1; stp <= 8; stp <<= 1)
#pragma unroll
      for (int r2 = 0; r2 < 4; ++r2)
        tmax[r2] = fmaxf(tmax[r2], __shfl_xor(tmax[r2], stp));

    bool ok = true;
#pragma unroll
    for (int r2 = 0; r2 < 4; ++r2) ok = ok && (tmax[r2] <= mprev[r2] + 8.0f);
    const bool skip = __all(ok ? 1 : 0);

    float mnew[4], psum[4];
#pragma unroll
    for (int r2 = 0; r2 < 4; ++r2) {
      mnew[r2] = skip ? mprev[r2] : fmaxf(mprev[r2], tmax[r2]);
      float ps = 0.f;
#pragma unroll
      for (int n = 0; n < 8; ++n) {
        float pv = exp2f(s[n][r2] - mnew[r2]);
        s[n][r2] = pv;
        ps += pv;
      }
      psum[r2] = ps;
    }
#pragma unroll
    for (int stp = 1; stp <= 8; stp <<= 1)
#pragma unroll
      for (int r2 = 0; r2 < 4; ++r2)
        psum[r2] += __shfl_xor(psum[r2], stp);

#pragma unroll
    for (int r2 = 0; r2 < 4; ++r2) {
      if (skip) {
        lsum[r2] += psum[r2];
      } else {
        float alpha = exp2f(mprev[r2] - mnew[r2]);
        lsum[r2] = lsum[r2] * alpha + psum[r2];
        mprev[r2] = mnew[r2];
#pragma unroll
        for (int dn = 0; dn < 8; ++dn) o[dn][r2] *= alpha;
      }
    }

    // ---- PV in two passes; P [16][64]/wave in its own region ----
    unsigned short* Pw = &lds[49152 + wid * 1024];
    const unsigned short* Vb = &lds[32768];
#pragma unroll
    for (int pass = 0; pass < 2; ++pass) {
#pragma unroll
      for (int nl = 0; nl < 4; ++nl)
#pragma unroll
        for (int r2 = 0; r2 < 4; ++r2) {
          int row = rgrp + r2;
          int col = nl * 16 + rowA;
          Pw[row * 64 + (col ^ ((row & 7) << 3))] = f2bf(s[pass * 4 + nl][r2]);
        }
      // per-wave DS ordering: compiler inserts lgkmcnt waits before reads
      __builtin_amdgcn_s_setprio(1);
#pragma unroll
      for (int kkl = 0; kkl < 2; ++kkl) {
        const int kk = pass * 2 + kkl;
        bf16x8 pa;
        {
          int row = rowA;
          int col0 = kkl * 32 + kgrp;
          pa = *(const bf16x8*)&Pw[row * 64 + (col0 ^ ((row & 7) << 3))];
        }
#pragma unroll
        for (int dn = 0; dn < 8; ++dn) {
          int row = dn * 16 + rowA;
          int ch  = (kk * 4 + kg) ^ (row & 7);
          bf16x8 vb = *(const bf16x8*)&Vb[row * 128 + ch * 8];
          o[dn] = __builtin_amdgcn_mfma_f32_16x16x32_bf16(pa, vb, o[dn], 0, 0, 0);
        }
      }
      __builtin_amdgcn_s_setprio(0);
    }

    // ---- segment epilogue: normalize and write ----
    if (it == nt - 1) {
      float rinv[4];
#pragma unroll
      for (int r2 = 0; r2 < 4; ++r2) rinv[r2] = 1.0f / lsum[r2];
#pragma unroll
      for (int dn = 0; dn < 8; ++dn)
#pragma unroll
        for (int r2 = 0; r2 < 4; ++r2) {
          float v = o[dn][r2] * rinv[r2];
          int t = q0w + rgrp + r2;
          int col = h * 128 + dn * 16 + rowA;
          obt[((size_t)b * 2048 + t) * 2048 + col] = f2bf(v);
        }
    }

    __syncthreads(); // all V/P reads done; V region + K buf u&1 reusable

    // ---- stage next: V(u+1) FIRST (older), then K(u+2) into buf u&1 ----
    if (u + 1 < total) {
      const int i1 = (u + 1 >= nt0) ? (u + 1 - nt0) : (u + 1);
      STAGE_V(i1 * 128);
      if (u + 2 < total) {
        const int i2 = (u + 2 >= nt0) ? (u + 2 - nt0) : (u + 2);
        STAGE_K(u & 1, i2 * 128);
      }
    }

    ++it;
    if (seg == 0 && it == nt0) { seg = 1; it = 0; }
  }
}

// ---- host launch -----------------------------------------------------------
extern "C" void kernel_launch(void* const* d_in, const int* in_sizes, int n_in,
                              void* d_out, int out_size, void* d_ws, size_t ws_size,
                              hipStream_t stream) {
  const float* x  = (const float*)d_in[0];
  const float* Wq = (const float*)d_in[2];
  const float* Wk = (const float*)d_in[3];
  const float* Wv = (const float*)d_in[4];
  const float* Wo = (const float*)d_in[5];
  float* out = (float*)d_out;

  char* ws = (char*)d_ws;
  unsigned short* xb  = (unsigned short*)(ws + 0);
  unsigned short* wqb = (unsigned short*)(ws + 16777216);
  unsigned short* wkb = (unsigned short*)(ws + 25165824);
  unsigned short* wvb = (unsigned short*)(ws + 33554432);
  unsigned short* wob = (unsigned short*)(ws + 41943040);
  unsigned short* qb  = (unsigned short*)(ws + 50331648);
  unsigned short* kb  = (unsigned short*)(ws + 67108864);
  unsigned short* vtb = (unsigned short*)(ws + 83886080);
  unsigned short* obt = (unsigned short*)(ws + 100663296);
  float* ct = (float*)(ws + 117440512);
  float* st = (float*)(ws + 117964800);

  k_cvt5<<<2048, 256, 0, stream>>>(x, Wq, Wk, Wv, Wo, xb, wqb, wkb, wvb, wob, ct, st);
  dim3 gq(48, 16); // merged QKV: 768 blocks = 3 even rounds; RoPE fused (vec)
  k_gemm256n128<1><<<gq, 512, 0, stream>>>(xb, wqb, wkb, wvb, nullptr, qb, kb, vtb, ct, st);
  k_flash<<<256, 512, 0, stream>>>(qb, kb, vtb, obt);
  dim3 go(16, 16); // Wo: 256 blocks = 1 full-chip round
  k_gemm256n128<0><<<go, 512, 0, stream>>>(obt, wob, nullptr, nullptr, out, nullptr, nullptr, nullptr, nullptr, nullptr);
}

// Round 30
// 247.796 us; speedup vs baseline: 1.0948x; 1.0001x over previous
//
#include <hip/hip_runtime.h>
#include <stdint.h>

#define AS1 __attribute__((address_space(1)))
#define AS3 __attribute__((address_space(3)))

using bf16x8 = __attribute__((ext_vector_type(8))) short;
using f32x4  = __attribute__((ext_vector_type(4))) float;

// ---- helpers -------------------------------------------------------------
__device__ __forceinline__ unsigned short f2bf(float f) {
  union { float f; unsigned u; } v; v.f = f;
  return (unsigned short)((v.u + 0x7FFFu + ((v.u >> 16) & 1u)) >> 16); // RNE
}
__device__ __forceinline__ float bf2f(unsigned short h) {
  union { unsigned u; float f; } v; v.u = ((unsigned)h) << 16;
  return v.f;
}
// async global->LDS, 16B per lane; lds dest must be wave-uniform base (HW adds lane*16)
__device__ __forceinline__ void gload_lds16(const void* g, void* l) {
  __builtin_amdgcn_global_load_lds((AS1 const void*)g, (AS3 void*)l, 16, 0, 0);
}

// ---- fused fp32->bf16 convert (x + 4 weights) + RoPE tables, one launch ----
__global__ void k_cvt5(const float* __restrict__ x,  const float* __restrict__ wq,
                       const float* __restrict__ wk, const float* __restrict__ wv,
                       const float* __restrict__ wo,
                       unsigned short* __restrict__ xb,  unsigned short* __restrict__ wqb,
                       unsigned short* __restrict__ wkb, unsigned short* __restrict__ wvb,
                       unsigned short* __restrict__ wob,
                       float* __restrict__ ct, float* __restrict__ st) {
  int idx = blockIdx.x * blockDim.x + threadIdx.x;
  int stride = gridDim.x * blockDim.x;
  for (int i = idx; i < 6422528; i += stride) {
    if (i >= 6291456) { // rope tables
      int j = i - 6291456;
      int t = j >> 6, fi = j & 63;
      float invf = exp2f(-(float)fi * (13.287712379549449f / 64.0f));
      float a = (float)t * invf;
      ct[j] = cosf(a);
      st[j] = sinf(a);
      continue;
    }
    const float* src; unsigned short* dst; int off;
    if (i < 2097152) { src = x; dst = xb; off = i; }
    else {
      int j = i - 2097152;
      int w = j >> 20;            // 1,048,576 float4 per weight
      off = j & 1048575;
      src = (w == 0) ? wq : (w == 1) ? wk : (w == 2) ? wv : wo;
      dst = (w == 0) ? wqb : (w == 1) ? wkb : (w == 2) ? wvb : wob;
    }
    float4 f = ((const float4*)src)[off];
    ushort4 o;
    o.x = f2bf(f.x); o.y = f2bf(f.y); o.z = f2bf(f.z); o.w = f2bf(f.w);
    ((ushort4*)dst)[off] = o;
  }
}

// ---- 256x128 GEMM, TRIPLE-buffered counted-vmcnt pipeline + fused RoPE -----
// EXACT r28/r29 kernel (verified: QKV ~118us, Wo ~13us).
template <int MODE>
__global__ __launch_bounds__(512, 2) void k_gemm256n128(
    const unsigned short* __restrict__ Ag,
    const unsigned short* __restrict__ B0,
    const unsigned short* __restrict__ B1,
    const unsigned short* __restrict__ B2,
    float* __restrict__ outF,
    unsigned short* __restrict__ outQ,
    unsigned short* __restrict__ outK,
    unsigned short* __restrict__ outVT,
    const float* __restrict__ ctg,
    const float* __restrict__ stg) {
  // ush: A tbuf [3][16384] @0 (96KB) | B tbuf [3][4096..] @49152 (48KB) = 144KB
  __shared__ __align__(16) unsigned short lds[73728];

  const int tid = threadIdx.x;
  const int wid = tid >> 6, lane = tid & 63;
  const int wm = wid >> 1, wn = wid & 1;      // 4M x 2N wave grid
  const int rowA = lane & 15, kg = lane >> 4;
  const int rgrp = kg * 4;
  const int swz = rowA & 7;

  const int m0 = blockIdx.y * 256;
  const int n0g = blockIdx.x * 128;
  int w, n0;
  const unsigned short* Bg;
  if (MODE == 0) { w = 0; n0 = n0g; Bg = B0; }
  else { w = n0g >> 11; n0 = n0g & 2047; Bg = (w == 0) ? B0 : (w == 1) ? B1 : B2; }

  const int aBase = wm * 4096 + rowA * 64;
  const int bBase = wn * 4096 + rowA * 64;
  const int ch0 = (kg ^ swz) * 8;
  const int ch1 = ((4 + kg) ^ swz) * 8;

  const int grow = wid * 8 + (lane >> 3);
  const int gch  = ((lane & 7) ^ ((lane >> 3) & 7)) * 8;
  const int sdst = wid * 512;

  auto SA = [&](int dst, int t1, int c4) {
    gload_lds16(Ag + (size_t)(m0 + c4 * 64 + grow) * 2048 + t1 * 64 + gch,
                (void*)&lds[dst * 16384 + c4 * 4096 + sdst]);
  };
  auto SB = [&](int dst, int t1, int c2) {
    gload_lds16(Bg + (size_t)(n0 + c2 * 64 + grow) * 2048 + t1 * 64 + gch,
                (void*)&lds[49152 + dst * 8192 + c2 * 4096 + sdst]);
  };
  auto STAGE = [&](int dst, int t1) { // 6 gloads: the per-tile unit
    SA(dst, t1, 0); SA(dst, t1, 1); SA(dst, t1, 2); SA(dst, t1, 3);
    SB(dst, t1, 0); SB(dst, t1, 1);
  };

  f32x4 acc[4][4];
  const f32x4 z4 = {0.f, 0.f, 0.f, 0.f};
#pragma unroll
  for (int i = 0; i < 4; ++i)
#pragma unroll
    for (int j = 0; j < 4; ++j) acc[i][j] = z4;

  // prologue: stage t0 -> buf0 and t1 -> buf1; gate t0 (t1's 6 stay in flight)
  STAGE(0, 0);
  STAGE(1, 1);
  asm volatile("s_waitcnt vmcnt(6)" ::: "memory");
  __builtin_amdgcn_s_barrier();
  __builtin_amdgcn_sched_barrier(0);

  int cbuf = 0; // buffer holding tile t
  for (int t = 0; t < 32; ++t) {
    // ---- top: stage t+2 into the freed buffer (held t-1, synced) ----
    if (t + 2 < 32) {
      int nb = cbuf + 2; if (nb >= 3) nb -= 3;
      STAGE(nb, t + 2);
    }

    const int cA = cbuf * 16384, cB = 49152 + cbuf * 8192;
    bf16x8 af[4], bk[4];

    // ---- compute K-tile t from buf cbuf (both kk halves, 32 MFMA) ----
    __builtin_amdgcn_s_setprio(1);
#pragma unroll
    for (int i = 0; i < 4; ++i) af[i] = *(const bf16x8*)&lds[cA + aBase + i * 1024 + ch0];
#pragma unroll
    for (int j = 0; j < 4; ++j) bk[j] = *(const bf16x8*)&lds[cB + bBase + j * 1024 + ch0];
#pragma unroll
    for (int i = 0; i < 4; ++i)
#pragma unroll
      for (int j = 0; j < 4; ++j)
        acc[i][j] = __builtin_amdgcn_mfma_f32_16x16x32_bf16(af[i], bk[j], acc[i][j], 0, 0, 0);
#pragma unroll
    for (int i = 0; i < 4; ++i) af[i] = *(const bf16x8*)&lds[cA + aBase + i * 1024 + ch1];
#pragma unroll
    for (int j = 0; j < 4; ++j) bk[j] = *(const bf16x8*)&lds[cB + bBase + j * 1024 + ch1];
#pragma unroll
    for (int i = 0; i < 4; ++i)
#pragma unroll
      for (int j = 0; j < 4; ++j)
        acc[i][j] = __builtin_amdgcn_mfma_f32_16x16x32_bf16(af[i], bk[j], acc[i][j], 0, 0, 0);
    __builtin_amdgcn_s_setprio(0);

    if (t < 31) {
      // all waves done reading buf cbuf (it is re-staged at top of t+1)
      asm volatile("s_waitcnt lgkmcnt(0)" ::: "memory");
      __builtin_amdgcn_s_barrier();
      __builtin_amdgcn_sched_barrier(0);
      if (t + 2 < 32) {
        asm volatile("s_waitcnt vmcnt(6)" ::: "memory");  // t+1 retired; t+2 flying
      } else {
        asm volatile("s_waitcnt vmcnt(0)" ::: "memory");  // tail: drain t+1
      }
      __builtin_amdgcn_s_barrier();                       // publish t+1
      __builtin_amdgcn_sched_barrier(0);
    }

    cbuf = (cbuf + 1 == 3) ? 0 : cbuf + 1;
  }

  // ---- epilogue ----
  if (MODE == 1 && w < 2) {
    // fused RoPE: stage acc as bf16 [256][128] in LDS, pair (d, d+64)
    __syncthreads(); // all waves past their final tile-buffer reads
    unsigned short* Eb = lds;
#pragma unroll
    for (int i = 0; i < 4; ++i)
#pragma unroll
      for (int j = 0; j < 4; ++j)
#pragma unroll
        for (int r = 0; r < 4; ++r) {
          int ml = wm * 64 + i * 16 + rgrp + r;
          int dl = wn * 64 + j * 16 + rowA;
          Eb[ml * 128 + dl] = f2bf(acc[i][j][r]);
        }
    __syncthreads();
    unsigned short* C = w ? outK : outQ;
    const int h = n0 >> 7;            // BN=128: exactly one head per block
    const int d0 = (tid & 15) * 4;    // 4 consecutive d per thread
    const int g  = tid >> 4;          // 32 groups x 8 rows
    const float SC2 = 0.12751659974141322f; // (1/sqrt(128))*log2(e), Q only
#pragma unroll
    for (int mi = 0; mi < 8; ++mi) {
      int m = g * 8 + mi;
      int gm = m0 + m;
      int t = gm & 2047, b = gm >> 11;
      ushort4 a1 = *(const ushort4*)&Eb[m * 128 + d0];
      ushort4 a2 = *(const ushort4*)&Eb[m * 128 + d0 + 64];
      float4 cc = *(const float4*)&ctg[t * 64 + d0];
      float4 ss = *(const float4*)&stg[t * 64 + d0];
      float x1[4] = {bf2f(a1.x), bf2f(a1.y), bf2f(a1.z), bf2f(a1.w)};
      float x2[4] = {bf2f(a2.x), bf2f(a2.y), bf2f(a2.z), bf2f(a2.w)};
      float cv[4] = {cc.x, cc.y, cc.z, cc.w};
      float sv[4] = {ss.x, ss.y, ss.z, ss.w};
      ushort4 o1, o2;
      unsigned short* po1 = (unsigned short*)&o1;
      unsigned short* po2 = (unsigned short*)&o2;
#pragma unroll
      for (int e = 0; e < 4; ++e) {
        float y1 = x1[e] * cv[e] - x2[e] * sv[e];
        float y2 = x2[e] * cv[e] + x1[e] * sv[e];
        if (w == 0) { y1 *= SC2; y2 *= SC2; }
        po1[e] = f2bf(y1);
        po2[e] = f2bf(y2);
      }
      size_t base = ((size_t)(b * 16 + h) * 2048 + t) * 128;
      *(ushort4*)&C[base + d0]      = o1;
      *(ushort4*)&C[base + d0 + 64] = o2;
    }
  } else {
#pragma unroll
    for (int i = 0; i < 4; ++i) {
#pragma unroll
      for (int j = 0; j < 4; ++j) {
        const int gm0 = m0 + wm * 64 + i * 16 + rgrp;
        const int gn  = n0 + wn * 64 + j * 16 + rowA;
        if (MODE == 0) {
#pragma unroll
          for (int r = 0; r < 4; ++r)
            outF[(size_t)(gm0 + r) * 2048 + gn] = acc[i][j][r];
        } else { // w == 2: transposed V
          int h = gn >> 7, dd = gn & 127;
          int b = gm0 >> 11, tt = gm0 & 2047;
          ushort4 pk;
          pk.x = f2bf(acc[i][j][0]); pk.y = f2bf(acc[i][j][1]);
          pk.z = f2bf(acc[i][j][2]); pk.w = f2bf(acc[i][j][3]);
          *(ushort4*)&outVT[(((size_t)(b * 16 + h)) * 128 + dd) * 2048 + tt] = pk;
        }
      }
    }
  }
}

// ---- flash attention fwd: 8 waves x 16 q-rows, K AND V double-buffered -----
// r29 + V double-buffer (144KB LDS, 1 block/CU). Issue order per tile: V
// BEFORE K (same tile), so the top gate vmcnt(8) (K(u) done; V(u+1)+K(u+1)=8
// newer) IMPLIES V(u) done -> the mid gate drops its vmcnt entirely
// (lgkmcnt(0)+barrier only). Every load flies a FULL iteration before its
// gate; one fewer vm wait per iteration. Epilogue stores / Q-frag loads only
// make gates conservative (over-wait), never unsafe.
__global__ __launch_bounds__(512) void k_flash(const unsigned short* __restrict__ q,
                                               const unsigned short* __restrict__ k,
                                               const unsigned short* __restrict__ vt,
                                               unsigned short* __restrict__ obt) {
  // ush: K dbuf [2][16384] @0 | V dbuf [2][16384] @32768 | P 8x1024 @65536
  __shared__ __align__(16) unsigned short lds[73728]; // 144 KiB

  const int tid = threadIdx.x;
  const int wid = tid >> 6, lane = tid & 63;   // wid 0..7
  const int rowA = lane & 15, kg = lane >> 4;
  const int kgrp = kg * 8, rgrp = kg * 4;

  const int bid = blockIdx.x;          // 0..255
  const int xcd = bid & 7;             // round-robin XCD dispatch (perf-only)
  const int r0  = bid >> 3;            // 0..31
  const int bh  = xcd * 4 + (r0 & 3);  // 4 heads per XCD chunk
  const int p   = r0 >> 2;             // 0..7
  const int b = bh >> 4, h = bh & 15;

  const int jbs[2] = {15 - p, p};      // heavy segment first
  const int nt0 = jbs[0] + 1, nt1 = jbs[1] + 1;
  const int total = nt0 + nt1;         // = 17 for every block

  const unsigned short* qh  = q  + (size_t)bh * 2048 * 128;
  const unsigned short* kh  = k  + (size_t)bh * 2048 * 128;
  const unsigned short* vth = vt + (size_t)bh * 128 * 2048;

  const int srow4 = wid * 4 + (lane >> 4); // 0..31
  auto STAGE_K = [&](int buf, int kv0) {
#pragma unroll
    for (int c = 0; c < 4; ++c) {
      int row = c * 32 + srow4;
      int ch  = (lane & 15) ^ (row & 7);
      gload_lds16(kh + (size_t)(kv0 + row) * 128 + ch * 8,
                  (void*)&lds[buf * 16384 + (c * 32 + wid * 4) * 128]);
    }
  };
  auto STAGE_V = [&](int buf, int kv0) {
#pragma unroll
    for (int c = 0; c < 4; ++c) {
      int row = c * 32 + srow4;            // d-dim row
      int ch  = (lane & 15) ^ (row & 7);
      gload_lds16(vth + (size_t)row * 2048 + kv0 + ch * 8,
                  (void*)&lds[32768 + buf * 16384 + (c * 32 + wid * 4) * 128]);
    }
  };

  const f32x4 z4 = {0.f, 0.f, 0.f, 0.f};
  bf16x8 qf[4];
  f32x4 o[8];
  float mprev[4], lsum[4];
  int q0w = 0;

  int seg = 0, it = 0;
  // prologue: V before K per tile (FIFO: waiting K(u) implies V(u) done).
  // Tiles 0 and 1 always exist in seg 0 (nt0 >= 9).
  STAGE_V(0, 0);
  STAGE_K(0, 0);
  STAGE_V(1, 128);
  STAGE_K(1, 128);

  for (int u = 0; u < total; ++u) {
    const int nt = (seg == 0) ? nt0 : nt1;
    const int kv0 = it * 128;

    // ---- top gate: K(u) done (=> V(u) done); V(u+1)+K(u+1) = 8 in flight ---
    if (u + 1 < total) { asm volatile("s_waitcnt vmcnt(8)" ::: "memory"); }
    else               { asm volatile("s_waitcnt vmcnt(0)" ::: "memory"); }
    __builtin_amdgcn_s_barrier();
    __builtin_amdgcn_sched_barrier(0);

    if (it == 0) {   // segment init: Q fragments (16 rows/wave) + state reset
      q0w = jbs[seg] * 128 + wid * 16;
#pragma unroll
      for (int kq = 0; kq < 4; ++kq)
        qf[kq] = *(const bf16x8*)(qh + (size_t)(q0w + rowA) * 128 + kq * 32 + kgrp);
#pragma unroll
      for (int dn = 0; dn < 8; ++dn) o[dn] = z4;
#pragma unroll
      for (int r2 = 0; r2 < 4; ++r2) { mprev[r2] = -1e30f; lsum[r2] = 0.f; }
    }

    // ---- S = Q K^T over 128 kv (swizzled LDS, K buffer u&1) ----
    const unsigned short* Kb = &lds[(u & 1) * 16384];
    f32x4 s[8];
#pragma unroll
    for (int n = 0; n < 8; ++n) s[n] = z4;
    __builtin_amdgcn_s_setprio(1);
#pragma unroll
    for (int kq = 0; kq < 4; ++kq) {
#pragma unroll
      for (int n = 0; n < 8; ++n) {
        int row = n * 16 + rowA;
        int ch  = (kq * 4 + kg) ^ (row & 7);
        bf16x8 bkk = *(const bf16x8*)&Kb[row * 128 + ch * 8];
        s[n] = __builtin_amdgcn_mfma_f32_16x16x32_bf16(qf[kq], bkk, s[n], 0, 0, 0);
      }
    }
    __builtin_amdgcn_s_setprio(0);

    // ---- mid gate: K reads done (V(u) already complete via top gate) ----
    asm volatile("s_waitcnt lgkmcnt(0)" ::: "memory");
    __builtin_amdgcn_s_barrier();
    __builtin_amdgcn_sched_barrier(0);

    // ---- causal mask (only the diagonal tile) ----
    if (kv0 + 127 > q0w) {
#pragma unroll
      for (int n = 0; n < 8; ++n)
#pragma unroll
        for (int r2 = 0; r2 < 4; ++r2) {
          int qg = q0w + rgrp + r2;
          int kgl = kv0 + n * 16 + rowA;
          if (kgl > qg) s[n][r2] = -1e30f;
        }
    }

    // ---- online softmax (base-2), step-major trees, defer-max ----
    float tmax[4];
#pragma unroll
    for (int r2 = 0; r2 < 4; ++r2) {
      float t = s[0][r2];
#pragma unroll
      for (int n = 1; n < 8; ++n) t = fmaxf(t, s[n][r2]);
      tmax[r2] = t;
    }
#pragma unroll
    for (int stp = 1; stp <= 8; stp <<= 1)
#pragma unroll
      for (int r2 = 0; r2 < 4; ++r2)
        tmax[r2] = fmaxf(tmax[r2], __shfl_xor(tmax[r2], stp));

    bool ok = true;
#pragma unroll
    for (int r2 = 0; r2 < 4; ++r2) ok = ok && (tmax[r2] <= mprev[r2] + 8.0f);
    const bool skip = __all(ok ? 1 : 0);

    float mnew[4], psum[4];
#pragma unroll
    for (int r2 = 0; r2 < 4; ++r2) {
      mnew[r2] = skip ? mprev[r2] : fmaxf(mprev[r2], tmax[r2]);
      float ps = 0.f;
#pragma unroll
      for (int n = 0; n < 8; ++n) {
        float pv = exp2f(s[n][r2] - mnew[r2]);
        s[n][r2] = pv;
        ps += pv;
      }
      psum[r2] = ps;
    }
#pragma unroll
    for (int stp = 1; stp <= 8; stp <<= 1)
#pragma unroll
      for (int r2 = 0; r2 < 4; ++r2)
        psum[r2] += __shfl_xor(psum[r2], stp);

#pragma unroll
    for (int r2 = 0; r2 < 4; ++r2) {
      if (skip) {
        lsum[r2] += psum[r2];
      } else {
        float alpha = exp2f(mprev[r2] - mnew[r2]);
        lsum[r2] = lsum[r2] * alpha + psum[r2];
        mprev[r2] = mnew[r2];
#pragma unroll
        for (int dn = 0; dn < 8; ++dn) o[dn][r2] *= alpha;
      }
    }

    // ---- PV in two passes; P [16][64]/wave in its own region ----
    unsigned short* Pw = &lds[65536 + wid * 1024];
    const unsigned short* Vb = &lds[32768 + (u & 1) * 16384];
#pragma unroll
    for (int pass = 0; pass < 2; ++pass) {
#pragma unroll
      for (int nl = 0; nl < 4; ++nl)
#pragma unroll
        for (int r2 = 0; r2 < 4; ++r2) {
          int row = rgrp + r2;
          int col = nl * 16 + rowA;
          Pw[row * 64 + (col ^ ((row & 7) << 3))] = f2bf(s[pass * 4 + nl][r2]);
        }
      // per-wave DS ordering: compiler inserts lgkmcnt waits before reads
      __builtin_amdgcn_s_setprio(1);
#pragma unroll
      for (int kkl = 0; kkl < 2; ++kkl) {
        const int kk = pass * 2 + kkl;
        bf16x8 pa;
        {
          int row = rowA;
          int col0 = kkl * 32 + kgrp;
          pa = *(const bf16x8*)&Pw[row * 64 + (col0 ^ ((row & 7) << 3))];
        }
#pragma unroll
        for (int dn = 0; dn < 8; ++dn) {
          int row = dn * 16 + rowA;
          int ch  = (kk * 4 + kg) ^ (row & 7);
          bf16x8 vb = *(const bf16x8*)&Vb[row * 128 + ch * 8];
          o[dn] = __builtin_amdgcn_mfma_f32_16x16x32_bf16(pa, vb, o[dn], 0, 0, 0);
        }
      }
      __builtin_amdgcn_s_setprio(0);
    }

    // ---- segment epilogue: normalize and write ----
    if (it == nt - 1) {
      float rinv[4];
#pragma unroll
      for (int r2 = 0; r2 < 4; ++r2) rinv[r2] = 1.0f / lsum[r2];
#pragma unroll
      for (int dn = 0; dn < 8; ++dn)
#pragma unroll
        for (int r2 = 0; r2 < 4; ++r2) {
          float v = o[dn][r2] * rinv[r2];
          int t = q0w + rgrp + r2;
          int col = h * 128 + dn * 16 + rowA;
          obt[((size_t)b * 2048 + t) * 2048 + col] = f2bf(v);
        }
    }

    __syncthreads(); // all V/P reads done; K buf u&1 + V buf u&1 reusable

    // ---- stage tile u+2: V FIRST, then K (both into bufs u&1) ----
    if (u + 2 < total) {
      const int i2 = (u + 2 >= nt0) ? (u + 2 - nt0) : (u + 2);
      STAGE_V(u & 1, i2 * 128);
      STAGE_K(u & 1, i2 * 128);
    }

    ++it;
    if (seg == 0 && it == nt0) { seg = 1; it = 0; }
  }
}

// ---- host launch -----------------------------------------------------------
extern "C" void kernel_launch(void* const* d_in, const int* in_sizes, int n_in,
                              void* d_out, int out_size, void* d_ws, size_t ws_size,
                              hipStream_t stream) {
  const float* x  = (const float*)d_in[0];
  const float* Wq = (const float*)d_in[2];
  const float* Wk = (const float*)d_in[3];
  const float* Wv = (const float*)d_in[4];
  const float* Wo = (const float*)d_in[5];
  float* out = (float*)d_out;

  char* ws = (char*)d_ws;
  unsigned short* xb  = (unsigned short*)(ws + 0);
  unsigned short* wqb = (unsigned short*)(ws + 16777216);
  unsigned short* wkb = (unsigned short*)(ws + 25165824);
  unsigned short* wvb = (unsigned short*)(ws + 33554432);
  unsigned short* wob = (unsigned short*)(ws + 41943040);
  unsigned short* qb  = (unsigned short*)(ws + 50331648);
  unsigned short* kb  = (unsigned short*)(ws + 67108864);
  unsigned short* vtb = (unsigned short*)(ws + 83886080);
  unsigned short* obt = (unsigned short*)(ws + 100663296);
  float* ct = (float*)(ws + 117440512);
  float* st = (float*)(ws + 117964800);

  k_cvt5<<<2048, 256, 0, stream>>>(x, Wq, Wk, Wv, Wo, xb, wqb, wkb, wvb, wob, ct, st);
  dim3 gq(48, 16); // merged QKV: 768 blocks = 3 even rounds; RoPE fused (vec)
  k_gemm256n128<1><<<gq, 512, 0, stream>>>(xb, wqb, wkb, wvb, nullptr, qb, kb, vtb, ct, st);
  k_flash<<<256, 512, 0, stream>>>(qb, kb, vtb, obt);
  dim3 go(16, 16); // Wo: 256 blocks = 1 full-chip round
  k_gemm256n128<0><<<go, 512, 0, stream>>>(obt, wob, nullptr, nullptr, out, nullptr, nullptr, nullptr, nullptr, nullptr);
}